// Round 8
// baseline (2004.567 us; speedup 1.0000x reference)
//
#include <hip/hip_runtime.h>
#include <stdint.h>

#define NUMA 3
#define NUMC 80
#define CAP  32768
#define KTOP 400
#define POST 100
#define NBIN1 2048
#define EQCAP 1024
#define KEY0 0x3EE66666u   // __float_as_uint(0.45f): static compact threshold

typedef float f32x4 __attribute__((ext_vector_type(4)));

__device__ __forceinline__ float sigmoidf_(float x) { return 1.0f / (1.0f + expf(-x)); }
__device__ __forceinline__ unsigned uminu(unsigned a, unsigned b) { return a < b ? a : b; }

// ---------------- init: zero hist + cutb + ccnt + flags --------------------
__global__ void init_kernel(unsigned* __restrict__ p) {
    int i = blockIdx.x * blockDim.x + threadIdx.x;
    if (i < NBIN1 * 8 + 24) p[i] = 0;
}

// ---------------- static-threshold emit ------------------------------------
__device__ __forceinline__ void emit_st(float sc, unsigned idx, int b,
        unsigned* ccnt, unsigned* ckey, unsigned* cidx)
{
    unsigned key = __float_as_uint(sc);
    if (key >= KEY0) {
        unsigned pos = atomicAdd(&ccnt[b], 1u);
        if (pos < CAP) {
            ckey[(size_t)b * CAP + pos] = key;
            cidx[(size_t)b * CAP + pos] = idx;
        }
    }
}

// ---------------- main pass: single decode + static compact ----------------
// grid (10, 10, 24): x = hw-chunk (0-1: t0 scalar; 2-3: t1 vec; 4-9: t2 vec),
// y = class-group (8 classes), z = b*3 + a.  (R5-verified load structure.)
__global__ __launch_bounds__(256) void score_main(
        const float* __restrict__ t0, const float* __restrict__ t1,
        const float* __restrict__ t2,
        unsigned* __restrict__ ccnt, unsigned* __restrict__ ckey,
        unsigned* __restrict__ cidx)
{
    const int tid = threadIdx.x;
    const int ba = blockIdx.z;
    const int b = ba / 3, a = ba - 3 * b;
    const int c0 = blockIdx.y * 8;
    const int cx = blockIdx.x;

    if (cx < 2) {
        // ---- t0: HW=361, scalar (plane stride not 16B-aligned) ----
        const int hw = cx * 256 + tid;
        if (hw < 361) {
            const float* base = t0 + (size_t)(b * 255 + a * 85) * 361;
            float cr = base[4 * 361 + hw];
            const float* p0 = base + (size_t)(5 + c0) * 361 + hw;
            float x0 = p0[0 * 361], x1 = p0[1 * 361], x2 = p0[2 * 361], x3 = p0[3 * 361];
            float x4 = p0[4 * 361], x5 = p0[5 * 361], x6 = p0[6 * 361], x7 = p0[7 * 361];
            float cf = sigmoidf_(cr);
            unsigned ib = (unsigned)((hw * NUMA + a) * NUMC + c0);
            emit_st(sigmoidf_(x0) * cf, ib + 0, b, ccnt, ckey, cidx);
            emit_st(sigmoidf_(x1) * cf, ib + 1, b, ccnt, ckey, cidx);
            emit_st(sigmoidf_(x2) * cf, ib + 2, b, ccnt, ckey, cidx);
            emit_st(sigmoidf_(x3) * cf, ib + 3, b, ccnt, ckey, cidx);
            emit_st(sigmoidf_(x4) * cf, ib + 4, b, ccnt, ckey, cidx);
            emit_st(sigmoidf_(x5) * cf, ib + 5, b, ccnt, ckey, cidx);
            emit_st(sigmoidf_(x6) * cf, ib + 6, b, ccnt, ckey, cidx);
            emit_st(sigmoidf_(x7) * cf, ib + 7, b, ccnt, ckey, cidx);
        }
    } else {
        // ---- t1/t2: float4 ----
        const float* tip; int vHW, v, candOff;
        if (cx < 4) { tip = t1; vHW = 361;  v = (cx - 2) * 256 + tid; candOff = 86640; }
        else        { tip = t2; vHW = 1444; v = (cx - 4) * 256 + tid; candOff = 433200; }
        if (v < vHW) {
            const f32x4* bp = (const f32x4*)(tip + (size_t)(b * 255 + a * 85) * (size_t)(vHW * 4));
            f32x4 cv = bp[(size_t)4 * vHW + v];
            const f32x4* p0 = bp + (size_t)(5 + c0) * vHW + v;
            f32x4 s0 = p0[0 * (size_t)vHW], s1 = p0[1 * (size_t)vHW];
            f32x4 s2 = p0[2 * (size_t)vHW], s3 = p0[3 * (size_t)vHW];
            f32x4 s4 = p0[4 * (size_t)vHW], s5 = p0[5 * (size_t)vHW];
            f32x4 s6 = p0[6 * (size_t)vHW], s7 = p0[7 * (size_t)vHW];
            float cf0 = sigmoidf_(cv[0]), cf1 = sigmoidf_(cv[1]);
            float cf2 = sigmoidf_(cv[2]), cf3 = sigmoidf_(cv[3]);
            unsigned ib0 = (unsigned)(candOff + (v * 4 * NUMA + a) * NUMC + c0);
            #define EMIT4(S, U) do { \
                unsigned ib = ib0 + (U); \
                emit_st(sigmoidf_((S)[0]) * cf0, ib,       b, ccnt, ckey, cidx); \
                emit_st(sigmoidf_((S)[1]) * cf1, ib + 240, b, ccnt, ckey, cidx); \
                emit_st(sigmoidf_((S)[2]) * cf2, ib + 480, b, ccnt, ckey, cidx); \
                emit_st(sigmoidf_((S)[3]) * cf3, ib + 720, b, ccnt, ckey, cidx); \
            } while (0)
            EMIT4(s0, 0); EMIT4(s1, 1); EMIT4(s2, 2); EMIT4(s3, 3);
            EMIT4(s4, 4); EMIT4(s5, 5); EMIT4(s6, 6); EMIT4(s7, 7);
            #undef EMIT4
        }
    }
}

// ---------------- validate static cut --------------------------------------
__global__ void validate_kernel(unsigned* __restrict__ ccnt, unsigned* __restrict__ flags) {
    int b = threadIdx.x;
    if (b < 8) {
        unsigned c = ccnt[b];
        bool ok = (c >= KTOP) && (c <= CAP);
        flags[b] = ok ? 1u : 0u;
        if (!ok) ccnt[b] = 0;
    }
}

// ---------------- fallback: full histogram (early-exits when valid) --------
__global__ __launch_bounds__(256) void fb_hist(
        const float* __restrict__ t0, const float* __restrict__ t1,
        const float* __restrict__ t2,
        unsigned* __restrict__ hist, const unsigned* __restrict__ flags)
{
    const int ba = blockIdx.z;
    const int b = ba / 3, a = ba - 3 * b;
    if (flags[b]) return;
    __shared__ unsigned lh[NBIN1];
    const int tid = threadIdx.x;
    for (int i = tid; i < NBIN1; i += 256) lh[i] = 0;
    __syncthreads();
    const int c0 = blockIdx.y * 8;
    const int cx = blockIdx.x;
    if (cx < 2) {
        const int hw = cx * 256 + tid;
        if (hw < 361) {
            const float* base = t0 + (size_t)(b * 255 + a * 85) * 361;
            float cf = sigmoidf_(base[4 * 361 + hw]);
            for (int u = 0; u < 8; u++) {
                float sc = sigmoidf_(base[(size_t)(5 + c0 + u) * 361 + hw]) * cf;
                atomicAdd(&lh[__float_as_uint(sc) >> 19], 1u);
            }
        }
    } else {
        const float* tip; int vHW, v;
        if (cx < 4) { tip = t1; vHW = 361;  v = (cx - 2) * 256 + tid; }
        else        { tip = t2; vHW = 1444; v = (cx - 4) * 256 + tid; }
        if (v < vHW) {
            const f32x4* bp = (const f32x4*)(tip + (size_t)(b * 255 + a * 85) * (size_t)(vHW * 4));
            f32x4 cv = bp[(size_t)4 * vHW + v];
            float cf[4] = { sigmoidf_(cv[0]), sigmoidf_(cv[1]), sigmoidf_(cv[2]), sigmoidf_(cv[3]) };
            for (int u = 0; u < 8; u++) {
                f32x4 s = bp[(size_t)(5 + c0 + u) * vHW + v];
                for (int l = 0; l < 4; l++)
                    atomicAdd(&lh[__float_as_uint(sigmoidf_(s[l]) * cf[l]) >> 19], 1u);
            }
        }
    }
    __syncthreads();
    unsigned* gh = hist + b * NBIN1;
    for (int i = tid; i < NBIN1; i += 256) {
        unsigned v2 = lh[i];
        if (v2) atomicAdd(&gh[i], v2);
    }
}

// ---------------- wave-parallel rank select over an LDS histogram ----------
__device__ __forceinline__ void wave_select(const unsigned* h, int nbins, unsigned rank,
                                            unsigned* resv, int tid)
{
    if (tid >= 64) return;
    const int lane = tid;
    const int cs = nbins >> 6;
    unsigned v = 0;
    for (int k = 0; k < cs; k++) {
        int off = (k + lane) & (cs - 1);
        v += h[lane * cs + off];
    }
    unsigned S = v;
    #pragma unroll
    for (int o = 1; o < 64; o <<= 1) {
        unsigned t = (unsigned)__shfl_down((int)S, o);
        if (lane + o < 64) S += t;
    }
    unsigned long long bm = __ballot(S >= rank);
    int C = 63 - __builtin_clzll(bm);
    unsigned SC = (unsigned)__builtin_amdgcn_readlane((int)S, C);
    unsigned vC = (unsigned)__builtin_amdgcn_readlane((int)v, C);
    unsigned rem = rank - (SC - vC);
    unsigned w = (lane < cs) ? h[C * cs + lane] : 0u;
    unsigned T = w;
    #pragma unroll
    for (int o = 1; o < 64; o <<= 1) {
        unsigned t = (unsigned)__shfl_down((int)T, o);
        if (lane + o < 64) T += t;
    }
    unsigned long long bm2 = __ballot((T >= rem) && (lane < cs));
    int B = 63 - __builtin_clzll(bm2);
    unsigned TB = (unsigned)__builtin_amdgcn_readlane((int)T, B);
    unsigned wB = (unsigned)__builtin_amdgcn_readlane((int)w, B);
    if (lane == 0) {
        resv[0] = (unsigned)(C * cs + B);
        resv[1] = rem - (TB - wB);
    }
}

// ---------------- fallback: find rank-400 bin ------------------------------
__global__ __launch_bounds__(256) void fb_cut(const unsigned* __restrict__ hist,
                                              unsigned* __restrict__ cutb,
                                              const unsigned* __restrict__ flags) {
    int b = blockIdx.x;
    if (flags[b]) return;
    __shared__ unsigned h[NBIN1];
    __shared__ unsigned resv[2];
    for (int i = threadIdx.x; i < NBIN1; i += 256) h[i] = hist[b * NBIN1 + i];
    __syncthreads();
    wave_select(h, NBIN1, KTOP, resv, threadIdx.x);
    __syncthreads();
    if (threadIdx.x == 0) cutb[b] = resv[0];
}

// ---------------- fallback: recompact with exact bin cut -------------------
__global__ __launch_bounds__(256) void fb_compact(
        const float* __restrict__ t0, const float* __restrict__ t1,
        const float* __restrict__ t2,
        const unsigned* __restrict__ cutb, unsigned* __restrict__ ccnt,
        unsigned* __restrict__ ckey, unsigned* __restrict__ cidx,
        const unsigned* __restrict__ flags)
{
    const int ba = blockIdx.z;
    const int b = ba / 3, a = ba - 3 * b;
    if (flags[b]) return;
    const int tid = threadIdx.x;
    const int c0 = blockIdx.y * 8;
    const int cx = blockIdx.x;
    unsigned cutkey = cutb[b] << 19;

    if (cx < 2) {
        const int hw = cx * 256 + tid;
        if (hw < 361) {
            const float* base = t0 + (size_t)(b * 255 + a * 85) * 361;
            float cf = sigmoidf_(base[4 * 361 + hw]);
            for (int u = 0; u < 8; u++) {
                float sc = sigmoidf_(base[(size_t)(5 + c0 + u) * 361 + hw]) * cf;
                unsigned key = __float_as_uint(sc);
                if (key >= cutkey) {
                    unsigned pos = atomicAdd(&ccnt[b], 1u);
                    if (pos < CAP) {
                        ckey[(size_t)b * CAP + pos] = key;
                        cidx[(size_t)b * CAP + pos] = (unsigned)((hw * NUMA + a) * NUMC + c0 + u);
                    }
                }
            }
        }
    } else {
        const float* tip; int vHW, v, candOff;
        if (cx < 4) { tip = t1; vHW = 361;  v = (cx - 2) * 256 + tid; candOff = 86640; }
        else        { tip = t2; vHW = 1444; v = (cx - 4) * 256 + tid; candOff = 433200; }
        if (v < vHW) {
            const f32x4* bp = (const f32x4*)(tip + (size_t)(b * 255 + a * 85) * (size_t)(vHW * 4));
            f32x4 cv = bp[(size_t)4 * vHW + v];
            float cf[4] = { sigmoidf_(cv[0]), sigmoidf_(cv[1]), sigmoidf_(cv[2]), sigmoidf_(cv[3]) };
            unsigned ib0 = (unsigned)(candOff + (v * 4 * NUMA + a) * NUMC + c0);
            for (int u = 0; u < 8; u++) {
                f32x4 s = bp[(size_t)(5 + c0 + u) * vHW + v];
                for (int l = 0; l < 4; l++) {
                    float sc = sigmoidf_(s[l]) * cf[l];
                    unsigned key = __float_as_uint(sc);
                    if (key >= cutkey) {
                        unsigned pos = atomicAdd(&ccnt[b], 1u);
                        if (pos < CAP) {
                            ckey[(size_t)b * CAP + pos] = key;
                            cidx[(size_t)b * CAP + pos] = ib0 + (unsigned)u + (unsigned)l * 240;
                        }
                    }
                }
            }
        }
    }
}

// ---------------- per-image: exact top-400, NMS, output --------------------
__global__ __launch_bounds__(512) void nms_kernel(
        const float* __restrict__ t0, const float* __restrict__ t1,
        const float* __restrict__ t2,
        const float* __restrict__ anc0, const float* __restrict__ anc1,
        const float* __restrict__ anc2,
        const unsigned* __restrict__ ckey, const unsigned* __restrict__ cidx,
        const unsigned* __restrict__ ccnt, float* __restrict__ out)
{
    const int b = blockIdx.x;
    const int tid = threadIdx.x;
    const int T = 512;

    __shared__ unsigned hist[4096];
    __shared__ unsigned resv[2];
    __shared__ unsigned selk[512], seli[512];
    __shared__ unsigned eqi[EQCAP];
    __shared__ float sx1[KTOP], sy1[KTOP], sx2[KTOP], sy2[KTOP], ssc[KTOP];
    __shared__ int   scid[KTOP];
    __shared__ unsigned long long maskS[KTOP * 7];
    __shared__ unsigned long long vkeep[7];
    __shared__ unsigned cnts[2];
    __shared__ float oid[POST], osc[POST], obb[POST * 4];

    const unsigned n = uminu(ccnt[b], (unsigned)CAP);
    const unsigned* ck = ckey + (size_t)b * CAP;
    const unsigned* ci = cidx + (size_t)b * CAP;

    // ---- Round 1: bits [30:19] ----
    for (int i = tid; i < NBIN1; i += T) hist[i] = 0;
    __syncthreads();
    for (unsigned i = tid; i < n; i += T) atomicAdd(&hist[ck[i] >> 19], 1u);
    __syncthreads();
    wave_select(hist, NBIN1, KTOP, resv, tid);
    __syncthreads();
    unsigned b1 = resv[0], r2 = resv[1];
    __syncthreads();

    // ---- Round 2: bits [18:7] ----
    for (int i = tid; i < 4096; i += T) hist[i] = 0;
    __syncthreads();
    for (unsigned i = tid; i < n; i += T) {
        unsigned k = ck[i];
        if ((k >> 19) == b1) atomicAdd(&hist[(k >> 7) & 0xFFFu], 1u);
    }
    __syncthreads();
    wave_select(hist, 4096, r2, resv, tid);
    __syncthreads();
    unsigned b2 = resv[0], r3 = resv[1];
    __syncthreads();

    // ---- Round 3: bits [6:0] ----
    for (int i = tid; i < 128; i += T) hist[i] = 0;
    __syncthreads();
    unsigned pref = (b1 << 12) | b2;
    for (unsigned i = tid; i < n; i += T) {
        unsigned k = ck[i];
        if ((k >> 7) == pref) atomicAdd(&hist[k & 127u], 1u);
    }
    __syncthreads();
    wave_select(hist, 128, r3, resv, tid);
    __syncthreads();
    unsigned b3 = resv[0], needEq = resv[1];
    unsigned K400 = (b1 << 19) | (b2 << 7) | b3;
    __syncthreads();

    // ---- compaction ----
    selk[tid] = 0u; seli[tid] = 0xFFFFFFFFu;
    for (int i = tid; i < EQCAP; i += T) eqi[i] = 0xFFFFFFFFu;
    if (tid == 0) { cnts[0] = 0; cnts[1] = 0; }
    __syncthreads();
    for (unsigned i = tid; i < n; i += T) {
        unsigned k = ck[i];
        if (k > K400) {
            unsigned p = atomicAdd(&cnts[0], 1u);
            if (p < KTOP) { selk[p] = k; seli[p] = ci[i]; }
        } else if (k == K400) {
            unsigned q = atomicAdd(&cnts[1], 1u);
            if (q < EQCAP) eqi[q] = ci[i];
        }
    }
    __syncthreads();
    unsigned selCnt = uminu(cnts[0], (unsigned)KTOP);
    unsigned eqN   = uminu(cnts[1], (unsigned)EQCAP);

    // ---- tie list: only sort if we must pick a strict subset ----
    if (eqN > needEq) {
        int P2 = 1; while ((unsigned)P2 < eqN) P2 <<= 1;
        for (int k2 = 2; k2 <= P2; k2 <<= 1) {
            for (int j = k2 >> 1; j > 0; j >>= 1) {
                __syncthreads();
                for (int i = tid; i < P2; i += T) {
                    int ixj = i ^ j;
                    if (ixj > i && ixj < P2) {
                        unsigned va = eqi[i], vb = eqi[ixj];
                        bool up = ((i & k2) == 0);
                        if (up ? (va > vb) : (va < vb)) { eqi[i] = vb; eqi[ixj] = va; }
                    }
                }
            }
        }
        __syncthreads();
    }
    for (unsigned t2v = tid; t2v < needEq; t2v += T) {
        unsigned p = selCnt + t2v;
        if (p < KTOP) { selk[p] = K400; seli[p] = eqi[t2v]; }
    }
    __syncthreads();

    // ---- bitonic sort 512 by (key desc, idx asc); j<64 passes in-wave ----
    for (int k2 = 2; k2 <= 512; k2 <<= 1) {
        int j = k2 >> 1;
        for (; j >= 64; j >>= 1) {
            __syncthreads();
            int i = tid, ixj = i ^ j;
            if (ixj > i) {
                unsigned ka = selk[i], kb = selk[ixj], ia = seli[i], ib = seli[ixj];
                bool before = (ka > kb) || (ka == kb && ia < ib);
                bool up = ((i & k2) == 0);
                if (up ? !before : before) {
                    selk[i] = kb; selk[ixj] = ka; seli[i] = ib; seli[ixj] = ia;
                }
            }
        }
        __syncthreads();
        for (; j > 0; j >>= 1) {
            int i = tid, ixj = i ^ j;
            if (ixj > i) {
                unsigned ka = selk[i], kb = selk[ixj], ia = seli[i], ib = seli[ixj];
                bool before = (ka > kb) || (ka == kb && ia < ib);
                bool up = ((i & k2) == 0);
                if (up ? !before : before) {
                    selk[i] = kb; selk[ixj] = ka; seli[i] = ib; seli[ixj] = ia;
                }
            }
        }
    }
    __syncthreads();

    // ---- gather + on-the-fly box decode for the 400 selected ----
    if (tid < KTOP) {
        unsigned idx = seli[tid];
        const float* tip; const float* anc; int HW, W, candOff; float strideF;
        if (idx < 86640u)       { tip = t0; anc = anc0; HW = 361;  W = 19; strideF = 32.f; candOff = 0; }
        else if (idx < 433200u) { tip = t1; anc = anc1; HW = 1444; W = 38; strideF = 16.f; candOff = 86640; }
        else                    { tip = t2; anc = anc2; HW = 5776; W = 76; strideF = 8.f;  candOff = 433200; }
        unsigned local = idx - (unsigned)candOff;
        int cls = (int)(local % NUMC);
        int nn  = (int)(local / NUMC);
        int a = nn % NUMA, hwl = nn / NUMA;
        const float* base = tip + (size_t)(b * 255 + a * 85) * HW + hwl;
        float tx = base[0];
        float ty = base[(size_t)HW];
        float tw = base[(size_t)2 * HW];
        float th = base[(size_t)3 * HW];
        float fx = (float)(hwl % W), fy = (float)(hwl / W);
        float cx = (sigmoidf_(tx) + fx) * strideF;
        float cy = (sigmoidf_(ty) + fy) * strideF;
        float hw_ = expf(tw) * anc[2 * a]     * 0.5f;
        float hh_ = expf(th) * anc[2 * a + 1] * 0.5f;
        sx1[tid] = cx - hw_; sy1[tid] = cy - hh_;
        sx2[tid] = cx + hw_; sy2[tid] = cy + hh_;
        ssc[tid] = __uint_as_float(selk[tid]);
        scid[tid] = cls;
    }
    __syncthreads();

    // ---- suppression bitmasks ----
    for (int p = tid; p < KTOP * 7; p += T) {
        int i = p / 7, w = p - i * 7;
        float x1i = sx1[i], y1i = sy1[i], x2i = sx2[i], y2i = sy2[i];
        float ai = fmaxf(x2i - x1i, 0.f) * fmaxf(y2i - y1i, 0.f);
        int cidI = scid[i];
        unsigned long long m = 0ull;
        int j0 = w * 64;
        int j1 = j0 + 64; if (j1 > KTOP) j1 = KTOP;
        int js = j0 > i + 1 ? j0 : i + 1;
        for (int j = js; j < j1; j++) {
            if (scid[j] != cidI) continue;
            float iw = fminf(x2i, sx2[j]) - fmaxf(x1i, sx1[j]);
            float ih = fminf(y2i, sy2[j]) - fmaxf(y1i, sy1[j]);
            iw = fmaxf(iw, 0.f); ih = fmaxf(ih, 0.f);
            float inter = iw * ih;
            float aj = fmaxf(sx2[j] - sx1[j], 0.f) * fmaxf(sy2[j] - sy1[j], 0.f);
            float iou = inter / (ai + aj - inter + 1e-12f);
            if (iou > 0.45f) m |= (1ull << (j - j0));
        }
        maskS[p] = m;
    }
    __syncthreads();

    // ---- greedy NMS: keep words in lanes 0..6; v_readlane broadcast -------
    if (tid < 64) {
        unsigned long long keep = 0ull;
        if (tid < 7) keep = (tid == 6) ? 0xFFFFull : ~0ull;
        unsigned long long m = (tid < 7) ? maskS[tid] : 0ull;
        for (int i = 0; i < KTOP; i++) {
            unsigned long long mn = (tid < 7 && i + 1 < KTOP) ? maskS[(i + 1) * 7 + tid] : 0ull;
            int w = i >> 6;
            unsigned klo = (unsigned)__builtin_amdgcn_readlane((int)(unsigned)(keep & 0xFFFFFFFFull), w);
            unsigned khi = (unsigned)__builtin_amdgcn_readlane((int)(unsigned)(keep >> 32), w);
            unsigned long long kw = ((unsigned long long)khi << 32) | klo;
            if ((kw >> (i & 63)) & 1ull) keep &= ~m;
            m = mn;
        }
        if (tid < 7) vkeep[tid] = keep;
    }
    __syncthreads();

    // ---- emit top-100, pad -1 ----
    if (tid < POST) { oid[tid] = -1.f; osc[tid] = -1.f; }
    if (tid < POST * 4) obb[tid] = -1.f;
    __syncthreads();
    if (tid < KTOP) {
        int w = tid >> 6, bp = tid & 63;
        unsigned long long kw = vkeep[w];
        if ((kw >> bp) & 1ull) {
            int r = 0;
            for (int q = 0; q < w; q++) r += __popcll(vkeep[q]);
            r += __popcll(kw & ((1ull << bp) - 1ull));
            if (r < POST) {
                oid[r] = (float)scid[tid];
                osc[r] = ssc[tid];
                obb[r * 4 + 0] = sx1[tid];
                obb[r * 4 + 1] = sy1[tid];
                obb[r * 4 + 2] = sx2[tid];
                obb[r * 4 + 3] = sy2[tid];
            }
        }
    }
    __syncthreads();
    if (tid < POST) {
        out[b * POST + tid]       = oid[tid];
        out[800 + b * POST + tid] = osc[tid];
    }
    if (tid < POST * 4) out[1600 + b * POST * 4 + tid] = obb[tid];
}

// ---------------------------------------------------------------------------
extern "C" void kernel_launch(void* const* d_in, const int* in_sizes, int n_in,
                              void* d_out, int out_size, void* d_ws, size_t ws_size,
                              hipStream_t stream)
{
    const float* tip0 = (const float*)d_in[0];
    const float* tip1 = (const float*)d_in[1];
    const float* tip2 = (const float*)d_in[2];
    const float* anc0 = (const float*)d_in[3];
    const float* anc1 = (const float*)d_in[4];
    const float* anc2 = (const float*)d_in[5];
    float* out = (float*)d_out;

    // ws: hist(8*2048) | cutb(8) | ccnt(8) | flags(8) | ckey(8*CAP) | cidx(8*CAP)
    unsigned* hist  = (unsigned*)d_ws;
    unsigned* cutb  = hist + 8 * NBIN1;
    unsigned* ccnt  = cutb + 8;
    unsigned* flags = ccnt + 8;
    unsigned* ckey  = flags + 8;
    unsigned* cidx  = ckey + (size_t)8 * CAP;

    init_kernel<<<(NBIN1 * 8 + 24 + 255) / 256, 256, 0, stream>>>(hist);

    dim3 g(10, 10, 24);
    score_main<<<g, 256, 0, stream>>>(tip0, tip1, tip2, ccnt, ckey, cidx);
    validate_kernel<<<1, 64, 0, stream>>>(ccnt, flags);
    fb_hist<<<g, 256, 0, stream>>>(tip0, tip1, tip2, hist, flags);
    fb_cut<<<8, 256, 0, stream>>>(hist, cutb, flags);
    fb_compact<<<g, 256, 0, stream>>>(tip0, tip1, tip2, cutb, ccnt, cidx ? ckey : ckey, cidx, flags);
    nms_kernel<<<8, 512, 0, stream>>>(tip0, tip1, tip2, anc0, anc1, anc2,
                                      ckey, cidx, ccnt, out);
}

// Round 9
// 270.256 us; speedup vs baseline: 7.4173x; 7.4173x over previous
//
#include <hip/hip_runtime.h>
#include <stdint.h>

#define NUMA 3
#define NUMC 80
#define CAP  49152
#define KTOP 400
#define POST 100
#define NBIN1 2048
#define EQCAP 1024
#define KEY0 0x3EE66666u   // __float_as_uint(0.45f): static compact threshold
#define LBUF 2048          // per-block LDS candidate buffer

typedef float f32x4 __attribute__((ext_vector_type(4)));

__device__ __forceinline__ float sigmoidf_(float x) { return 1.0f / (1.0f + expf(-x)); }
__device__ __forceinline__ unsigned uminu(unsigned a, unsigned b) { return a < b ? a : b; }

// ---------------- init: zero hist + cutb + ccnt + flags --------------------
__global__ void init_kernel(unsigned* __restrict__ p) {
    int i = blockIdx.x * blockDim.x + threadIdx.x;
    if (i < NBIN1 * 8 + 24) p[i] = 0;
}

// ---------------- main pass: single decode + LDS-buffered static compact ---
// grid (10, 10, 24): x = hw-chunk (0-1: t0 scalar; 2-3: t1 vec; 4-9: t2 vec),
// y = class-group (8 classes), z = b*3 + a.  (R5-verified load structure.)
// Candidates buffered in LDS; ONE global atomic per block (not per candidate).
__global__ __launch_bounds__(256) void score_main(
        const float* __restrict__ t0, const float* __restrict__ t1,
        const float* __restrict__ t2,
        unsigned* __restrict__ ccnt, unsigned* __restrict__ ckey,
        unsigned* __restrict__ cidx)
{
    __shared__ unsigned lkey[LBUF], lidx[LBUF];
    __shared__ unsigned lcnt, lbase;
    const int tid = threadIdx.x;
    if (tid == 0) lcnt = 0;
    __syncthreads();

    const int ba = blockIdx.z;
    const int b = ba / 3, a = ba - 3 * b;
    const int c0 = blockIdx.y * 8;
    const int cx = blockIdx.x;

    #define LEMIT(SC, IDX) do { \
        unsigned key_ = __float_as_uint(SC); \
        if (key_ >= KEY0) { \
            unsigned pos_ = atomicAdd(&lcnt, 1u); \
            if (pos_ < LBUF) { lkey[pos_] = key_; lidx[pos_] = (IDX); } \
        } \
    } while (0)

    if (cx < 2) {
        // ---- t0: HW=361, scalar (plane stride not 16B-aligned) ----
        const int hw = cx * 256 + tid;
        if (hw < 361) {
            const float* base = t0 + (size_t)(b * 255 + a * 85) * 361;
            float cr = base[4 * 361 + hw];
            const float* p0 = base + (size_t)(5 + c0) * 361 + hw;
            float x0 = p0[0 * 361], x1 = p0[1 * 361], x2 = p0[2 * 361], x3 = p0[3 * 361];
            float x4 = p0[4 * 361], x5 = p0[5 * 361], x6 = p0[6 * 361], x7 = p0[7 * 361];
            float cf = sigmoidf_(cr);
            unsigned ib = (unsigned)((hw * NUMA + a) * NUMC + c0);
            LEMIT(sigmoidf_(x0) * cf, ib + 0);
            LEMIT(sigmoidf_(x1) * cf, ib + 1);
            LEMIT(sigmoidf_(x2) * cf, ib + 2);
            LEMIT(sigmoidf_(x3) * cf, ib + 3);
            LEMIT(sigmoidf_(x4) * cf, ib + 4);
            LEMIT(sigmoidf_(x5) * cf, ib + 5);
            LEMIT(sigmoidf_(x6) * cf, ib + 6);
            LEMIT(sigmoidf_(x7) * cf, ib + 7);
        }
    } else {
        // ---- t1/t2: float4 ----
        const float* tip; int vHW, v, candOff;
        if (cx < 4) { tip = t1; vHW = 361;  v = (cx - 2) * 256 + tid; candOff = 86640; }
        else        { tip = t2; vHW = 1444; v = (cx - 4) * 256 + tid; candOff = 433200; }
        if (v < vHW) {
            const f32x4* bp = (const f32x4*)(tip + (size_t)(b * 255 + a * 85) * (size_t)(vHW * 4));
            f32x4 cv = bp[(size_t)4 * vHW + v];
            const f32x4* p0 = bp + (size_t)(5 + c0) * vHW + v;
            f32x4 s0 = p0[0 * (size_t)vHW], s1 = p0[1 * (size_t)vHW];
            f32x4 s2 = p0[2 * (size_t)vHW], s3 = p0[3 * (size_t)vHW];
            f32x4 s4 = p0[4 * (size_t)vHW], s5 = p0[5 * (size_t)vHW];
            f32x4 s6 = p0[6 * (size_t)vHW], s7 = p0[7 * (size_t)vHW];
            float cf0 = sigmoidf_(cv[0]), cf1 = sigmoidf_(cv[1]);
            float cf2 = sigmoidf_(cv[2]), cf3 = sigmoidf_(cv[3]);
            unsigned ib0 = (unsigned)(candOff + (v * 4 * NUMA + a) * NUMC + c0);
            #define EMIT4(S, U) do { \
                unsigned ib = ib0 + (U); \
                LEMIT(sigmoidf_((S)[0]) * cf0, ib); \
                LEMIT(sigmoidf_((S)[1]) * cf1, ib + 240); \
                LEMIT(sigmoidf_((S)[2]) * cf2, ib + 480); \
                LEMIT(sigmoidf_((S)[3]) * cf3, ib + 720); \
            } while (0)
            EMIT4(s0, 0); EMIT4(s1, 1); EMIT4(s2, 2); EMIT4(s3, 3);
            EMIT4(s4, 4); EMIT4(s5, 5); EMIT4(s6, 6); EMIT4(s7, 7);
            #undef EMIT4
        }
    }
    #undef LEMIT

    __syncthreads();
    if (tid == 0) {
        unsigned c = lcnt;
        if (c > LBUF) {
            atomicOr(&ccnt[b], 0x80000000u);   // force invalid -> exact fallback
            lbase = 0xFFFFFFFFu;
        } else {
            lbase = atomicAdd(&ccnt[b], c);
        }
    }
    __syncthreads();
    unsigned c = uminu(lcnt, (unsigned)LBUF);
    unsigned basep = lbase;
    if (basep != 0xFFFFFFFFu) {
        for (unsigned i = tid; i < c; i += 256) {
            unsigned p = basep + i;
            if (p < CAP) {
                ckey[(size_t)b * CAP + p] = lkey[i];
                cidx[(size_t)b * CAP + p] = lidx[i];
            }
        }
    }
}

// ---------------- validate static cut --------------------------------------
__global__ void validate_kernel(unsigned* __restrict__ ccnt, unsigned* __restrict__ flags) {
    int b = threadIdx.x;
    if (b < 8) {
        unsigned c = ccnt[b];
        bool ok = (c >= KTOP) && (c <= CAP);
        flags[b] = ok ? 1u : 0u;
        if (!ok) ccnt[b] = 0;
    }
}

// ---------------- fallback: full histogram (early-exits when valid) --------
__global__ __launch_bounds__(256) void fb_hist(
        const float* __restrict__ t0, const float* __restrict__ t1,
        const float* __restrict__ t2,
        unsigned* __restrict__ hist, const unsigned* __restrict__ flags)
{
    const int ba = blockIdx.z;
    const int b = ba / 3, a = ba - 3 * b;
    if (flags[b]) return;
    __shared__ unsigned lh[NBIN1];
    const int tid = threadIdx.x;
    for (int i = tid; i < NBIN1; i += 256) lh[i] = 0;
    __syncthreads();
    const int c0 = blockIdx.y * 8;
    const int cx = blockIdx.x;
    if (cx < 2) {
        const int hw = cx * 256 + tid;
        if (hw < 361) {
            const float* base = t0 + (size_t)(b * 255 + a * 85) * 361;
            float cf = sigmoidf_(base[4 * 361 + hw]);
            for (int u = 0; u < 8; u++) {
                float sc = sigmoidf_(base[(size_t)(5 + c0 + u) * 361 + hw]) * cf;
                atomicAdd(&lh[__float_as_uint(sc) >> 19], 1u);
            }
        }
    } else {
        const float* tip; int vHW, v;
        if (cx < 4) { tip = t1; vHW = 361;  v = (cx - 2) * 256 + tid; }
        else        { tip = t2; vHW = 1444; v = (cx - 4) * 256 + tid; }
        if (v < vHW) {
            const f32x4* bp = (const f32x4*)(tip + (size_t)(b * 255 + a * 85) * (size_t)(vHW * 4));
            f32x4 cv = bp[(size_t)4 * vHW + v];
            float cf[4] = { sigmoidf_(cv[0]), sigmoidf_(cv[1]), sigmoidf_(cv[2]), sigmoidf_(cv[3]) };
            for (int u = 0; u < 8; u++) {
                f32x4 s = bp[(size_t)(5 + c0 + u) * vHW + v];
                for (int l = 0; l < 4; l++)
                    atomicAdd(&lh[__float_as_uint(sigmoidf_(s[l]) * cf[l]) >> 19], 1u);
            }
        }
    }
    __syncthreads();
    unsigned* gh = hist + b * NBIN1;
    for (int i = tid; i < NBIN1; i += 256) {
        unsigned v2 = lh[i];
        if (v2) atomicAdd(&gh[i], v2);
    }
}

// ---------------- wave-parallel rank select over an LDS histogram ----------
__device__ __forceinline__ void wave_select(const unsigned* h, int nbins, unsigned rank,
                                            unsigned* resv, int tid)
{
    if (tid >= 64) return;
    const int lane = tid;
    const int cs = nbins >> 6;
    unsigned v = 0;
    for (int k = 0; k < cs; k++) {
        int off = (k + lane) & (cs - 1);
        v += h[lane * cs + off];
    }
    unsigned S = v;
    #pragma unroll
    for (int o = 1; o < 64; o <<= 1) {
        unsigned t = (unsigned)__shfl_down((int)S, o);
        if (lane + o < 64) S += t;
    }
    unsigned long long bm = __ballot(S >= rank);
    int C = 63 - __builtin_clzll(bm);
    unsigned SC = (unsigned)__builtin_amdgcn_readlane((int)S, C);
    unsigned vC = (unsigned)__builtin_amdgcn_readlane((int)v, C);
    unsigned rem = rank - (SC - vC);
    unsigned w = (lane < cs) ? h[C * cs + lane] : 0u;
    unsigned T = w;
    #pragma unroll
    for (int o = 1; o < 64; o <<= 1) {
        unsigned t = (unsigned)__shfl_down((int)T, o);
        if (lane + o < 64) T += t;
    }
    unsigned long long bm2 = __ballot((T >= rem) && (lane < cs));
    int B = 63 - __builtin_clzll(bm2);
    unsigned TB = (unsigned)__builtin_amdgcn_readlane((int)T, B);
    unsigned wB = (unsigned)__builtin_amdgcn_readlane((int)w, B);
    if (lane == 0) {
        resv[0] = (unsigned)(C * cs + B);
        resv[1] = rem - (TB - wB);
    }
}

// ---------------- fallback: find rank-400 bin ------------------------------
__global__ __launch_bounds__(256) void fb_cut(const unsigned* __restrict__ hist,
                                              unsigned* __restrict__ cutb,
                                              const unsigned* __restrict__ flags) {
    int b = blockIdx.x;
    if (flags[b]) return;
    __shared__ unsigned h[NBIN1];
    __shared__ unsigned resv[2];
    for (int i = threadIdx.x; i < NBIN1; i += 256) h[i] = hist[b * NBIN1 + i];
    __syncthreads();
    wave_select(h, NBIN1, KTOP, resv, threadIdx.x);
    __syncthreads();
    if (threadIdx.x == 0) cutb[b] = resv[0];
}

// ---------------- fallback: recompact with exact bin cut -------------------
__global__ __launch_bounds__(256) void fb_compact(
        const float* __restrict__ t0, const float* __restrict__ t1,
        const float* __restrict__ t2,
        const unsigned* __restrict__ cutb, unsigned* __restrict__ ccnt,
        unsigned* __restrict__ ckey, unsigned* __restrict__ cidx,
        const unsigned* __restrict__ flags)
{
    const int ba = blockIdx.z;
    const int b = ba / 3, a = ba - 3 * b;
    if (flags[b]) return;
    const int tid = threadIdx.x;
    const int c0 = blockIdx.y * 8;
    const int cx = blockIdx.x;
    unsigned cutkey = cutb[b] << 19;

    if (cx < 2) {
        const int hw = cx * 256 + tid;
        if (hw < 361) {
            const float* base = t0 + (size_t)(b * 255 + a * 85) * 361;
            float cf = sigmoidf_(base[4 * 361 + hw]);
            for (int u = 0; u < 8; u++) {
                float sc = sigmoidf_(base[(size_t)(5 + c0 + u) * 361 + hw]) * cf;
                unsigned key = __float_as_uint(sc);
                if (key >= cutkey) {
                    unsigned pos = atomicAdd(&ccnt[b], 1u);
                    if (pos < CAP) {
                        ckey[(size_t)b * CAP + pos] = key;
                        cidx[(size_t)b * CAP + pos] = (unsigned)((hw * NUMA + a) * NUMC + c0 + u);
                    }
                }
            }
        }
    } else {
        const float* tip; int vHW, v, candOff;
        if (cx < 4) { tip = t1; vHW = 361;  v = (cx - 2) * 256 + tid; candOff = 86640; }
        else        { tip = t2; vHW = 1444; v = (cx - 4) * 256 + tid; candOff = 433200; }
        if (v < vHW) {
            const f32x4* bp = (const f32x4*)(tip + (size_t)(b * 255 + a * 85) * (size_t)(vHW * 4));
            f32x4 cv = bp[(size_t)4 * vHW + v];
            float cf[4] = { sigmoidf_(cv[0]), sigmoidf_(cv[1]), sigmoidf_(cv[2]), sigmoidf_(cv[3]) };
            unsigned ib0 = (unsigned)(candOff + (v * 4 * NUMA + a) * NUMC + c0);
            for (int u = 0; u < 8; u++) {
                f32x4 s = bp[(size_t)(5 + c0 + u) * vHW + v];
                for (int l = 0; l < 4; l++) {
                    float sc = sigmoidf_(s[l]) * cf[l];
                    unsigned key = __float_as_uint(sc);
                    if (key >= cutkey) {
                        unsigned pos = atomicAdd(&ccnt[b], 1u);
                        if (pos < CAP) {
                            ckey[(size_t)b * CAP + pos] = key;
                            cidx[(size_t)b * CAP + pos] = ib0 + (unsigned)u + (unsigned)l * 240;
                        }
                    }
                }
            }
        }
    }
}

// ---------------- per-image: exact top-400, NMS, output --------------------
__global__ __launch_bounds__(512) void nms_kernel(
        const float* __restrict__ t0, const float* __restrict__ t1,
        const float* __restrict__ t2,
        const float* __restrict__ anc0, const float* __restrict__ anc1,
        const float* __restrict__ anc2,
        const unsigned* __restrict__ ckey, const unsigned* __restrict__ cidx,
        const unsigned* __restrict__ ccnt, float* __restrict__ out)
{
    const int b = blockIdx.x;
    const int tid = threadIdx.x;
    const int T = 512;

    __shared__ unsigned hist[4096];
    __shared__ unsigned resv[2];
    __shared__ unsigned selk[512], seli[512];
    __shared__ unsigned eqi[EQCAP];
    __shared__ float sx1[KTOP], sy1[KTOP], sx2[KTOP], sy2[KTOP], ssc[KTOP];
    __shared__ int   scid[KTOP];
    __shared__ unsigned long long maskS[KTOP * 7];
    __shared__ unsigned long long vkeep[7];
    __shared__ unsigned cnts[2];
    __shared__ float oid[POST], osc[POST], obb[POST * 4];

    const unsigned n = uminu(ccnt[b], (unsigned)CAP);
    const unsigned* ck = ckey + (size_t)b * CAP;
    const unsigned* ci = cidx + (size_t)b * CAP;

    // ---- Round 1: bits [30:19] ----
    for (int i = tid; i < NBIN1; i += T) hist[i] = 0;
    __syncthreads();
    for (unsigned i = tid; i < n; i += T) atomicAdd(&hist[ck[i] >> 19], 1u);
    __syncthreads();
    wave_select(hist, NBIN1, KTOP, resv, tid);
    __syncthreads();
    unsigned b1 = resv[0], r2 = resv[1];
    __syncthreads();

    // ---- Round 2: bits [18:7] ----
    for (int i = tid; i < 4096; i += T) hist[i] = 0;
    __syncthreads();
    for (unsigned i = tid; i < n; i += T) {
        unsigned k = ck[i];
        if ((k >> 19) == b1) atomicAdd(&hist[(k >> 7) & 0xFFFu], 1u);
    }
    __syncthreads();
    wave_select(hist, 4096, r2, resv, tid);
    __syncthreads();
    unsigned b2 = resv[0], r3 = resv[1];
    __syncthreads();

    // ---- Round 3: bits [6:0] ----
    for (int i = tid; i < 128; i += T) hist[i] = 0;
    __syncthreads();
    unsigned pref = (b1 << 12) | b2;
    for (unsigned i = tid; i < n; i += T) {
        unsigned k = ck[i];
        if ((k >> 7) == pref) atomicAdd(&hist[k & 127u], 1u);
    }
    __syncthreads();
    wave_select(hist, 128, r3, resv, tid);
    __syncthreads();
    unsigned b3 = resv[0], needEq = resv[1];
    unsigned K400 = (b1 << 19) | (b2 << 7) | b3;
    __syncthreads();

    // ---- compaction ----
    selk[tid] = 0u; seli[tid] = 0xFFFFFFFFu;
    for (int i = tid; i < EQCAP; i += T) eqi[i] = 0xFFFFFFFFu;
    if (tid == 0) { cnts[0] = 0; cnts[1] = 0; }
    __syncthreads();
    for (unsigned i = tid; i < n; i += T) {
        unsigned k = ck[i];
        if (k > K400) {
            unsigned p = atomicAdd(&cnts[0], 1u);
            if (p < KTOP) { selk[p] = k; seli[p] = ci[i]; }
        } else if (k == K400) {
            unsigned q = atomicAdd(&cnts[1], 1u);
            if (q < EQCAP) eqi[q] = ci[i];
        }
    }
    __syncthreads();
    unsigned selCnt = uminu(cnts[0], (unsigned)KTOP);
    unsigned eqN   = uminu(cnts[1], (unsigned)EQCAP);

    // ---- tie list: only sort if we must pick a strict subset ----
    if (eqN > needEq) {
        int P2 = 1; while ((unsigned)P2 < eqN) P2 <<= 1;
        for (int k2 = 2; k2 <= P2; k2 <<= 1) {
            for (int j = k2 >> 1; j > 0; j >>= 1) {
                __syncthreads();
                for (int i = tid; i < P2; i += T) {
                    int ixj = i ^ j;
                    if (ixj > i && ixj < P2) {
                        unsigned va = eqi[i], vb = eqi[ixj];
                        bool up = ((i & k2) == 0);
                        if (up ? (va > vb) : (va < vb)) { eqi[i] = vb; eqi[ixj] = va; }
                    }
                }
            }
        }
        __syncthreads();
    }
    for (unsigned t2v = tid; t2v < needEq; t2v += T) {
        unsigned p = selCnt + t2v;
        if (p < KTOP) { selk[p] = K400; seli[p] = eqi[t2v]; }
    }
    __syncthreads();

    // ---- bitonic sort 512 by (key desc, idx asc); j<64 passes in-wave ----
    for (int k2 = 2; k2 <= 512; k2 <<= 1) {
        int j = k2 >> 1;
        for (; j >= 64; j >>= 1) {
            __syncthreads();
            int i = tid, ixj = i ^ j;
            if (ixj > i) {
                unsigned ka = selk[i], kb = selk[ixj], ia = seli[i], ib = seli[ixj];
                bool before = (ka > kb) || (ka == kb && ia < ib);
                bool up = ((i & k2) == 0);
                if (up ? !before : before) {
                    selk[i] = kb; selk[ixj] = ka; seli[i] = ib; seli[ixj] = ia;
                }
            }
        }
        __syncthreads();
        for (; j > 0; j >>= 1) {
            int i = tid, ixj = i ^ j;
            if (ixj > i) {
                unsigned ka = selk[i], kb = selk[ixj], ia = seli[i], ib = seli[ixj];
                bool before = (ka > kb) || (ka == kb && ia < ib);
                bool up = ((i & k2) == 0);
                if (up ? !before : before) {
                    selk[i] = kb; selk[ixj] = ka; seli[i] = ib; seli[ixj] = ia;
                }
            }
        }
    }
    __syncthreads();

    // ---- gather + on-the-fly box decode for the 400 selected ----
    if (tid < KTOP) {
        unsigned idx = seli[tid];
        const float* tip; const float* anc; int HW, W, candOff; float strideF;
        if (idx < 86640u)       { tip = t0; anc = anc0; HW = 361;  W = 19; strideF = 32.f; candOff = 0; }
        else if (idx < 433200u) { tip = t1; anc = anc1; HW = 1444; W = 38; strideF = 16.f; candOff = 86640; }
        else                    { tip = t2; anc = anc2; HW = 5776; W = 76; strideF = 8.f;  candOff = 433200; }
        unsigned local = idx - (unsigned)candOff;
        int cls = (int)(local % NUMC);
        int nn  = (int)(local / NUMC);
        int a = nn % NUMA, hwl = nn / NUMA;
        const float* base = tip + (size_t)(b * 255 + a * 85) * HW + hwl;
        float tx = base[0];
        float ty = base[(size_t)HW];
        float tw = base[(size_t)2 * HW];
        float th = base[(size_t)3 * HW];
        float fx = (float)(hwl % W), fy = (float)(hwl / W);
        float cx = (sigmoidf_(tx) + fx) * strideF;
        float cy = (sigmoidf_(ty) + fy) * strideF;
        float hw_ = expf(tw) * anc[2 * a]     * 0.5f;
        float hh_ = expf(th) * anc[2 * a + 1] * 0.5f;
        sx1[tid] = cx - hw_; sy1[tid] = cy - hh_;
        sx2[tid] = cx + hw_; sy2[tid] = cy + hh_;
        ssc[tid] = __uint_as_float(selk[tid]);
        scid[tid] = cls;
    }
    __syncthreads();

    // ---- suppression bitmasks ----
    for (int p = tid; p < KTOP * 7; p += T) {
        int i = p / 7, w = p - i * 7;
        float x1i = sx1[i], y1i = sy1[i], x2i = sx2[i], y2i = sy2[i];
        float ai = fmaxf(x2i - x1i, 0.f) * fmaxf(y2i - y1i, 0.f);
        int cidI = scid[i];
        unsigned long long m = 0ull;
        int j0 = w * 64;
        int j1 = j0 + 64; if (j1 > KTOP) j1 = KTOP;
        int js = j0 > i + 1 ? j0 : i + 1;
        for (int j = js; j < j1; j++) {
            if (scid[j] != cidI) continue;
            float iw = fminf(x2i, sx2[j]) - fmaxf(x1i, sx1[j]);
            float ih = fminf(y2i, sy2[j]) - fmaxf(y1i, sy1[j]);
            iw = fmaxf(iw, 0.f); ih = fmaxf(ih, 0.f);
            float inter = iw * ih;
            float aj = fmaxf(sx2[j] - sx1[j], 0.f) * fmaxf(sy2[j] - sy1[j], 0.f);
            float iou = inter / (ai + aj - inter + 1e-12f);
            if (iou > 0.45f) m |= (1ull << (j - j0));
        }
        maskS[p] = m;
    }
    __syncthreads();

    // ---- greedy NMS: keep words in lanes 0..6; v_readlane broadcast -------
    if (tid < 64) {
        unsigned long long keep = 0ull;
        if (tid < 7) keep = (tid == 6) ? 0xFFFFull : ~0ull;
        unsigned long long m = (tid < 7) ? maskS[tid] : 0ull;
        for (int i = 0; i < KTOP; i++) {
            unsigned long long mn = (tid < 7 && i + 1 < KTOP) ? maskS[(i + 1) * 7 + tid] : 0ull;
            int w = i >> 6;
            unsigned klo = (unsigned)__builtin_amdgcn_readlane((int)(unsigned)(keep & 0xFFFFFFFFull), w);
            unsigned khi = (unsigned)__builtin_amdgcn_readlane((int)(unsigned)(keep >> 32), w);
            unsigned long long kw = ((unsigned long long)khi << 32) | klo;
            if ((kw >> (i & 63)) & 1ull) keep &= ~m;
            m = mn;
        }
        if (tid < 7) vkeep[tid] = keep;
    }
    __syncthreads();

    // ---- emit top-100, pad -1 ----
    if (tid < POST) { oid[tid] = -1.f; osc[tid] = -1.f; }
    if (tid < POST * 4) obb[tid] = -1.f;
    __syncthreads();
    if (tid < KTOP) {
        int w = tid >> 6, bp = tid & 63;
        unsigned long long kw = vkeep[w];
        if ((kw >> bp) & 1ull) {
            int r = 0;
            for (int q = 0; q < w; q++) r += __popcll(vkeep[q]);
            r += __popcll(kw & ((1ull << bp) - 1ull));
            if (r < POST) {
                oid[r] = (float)scid[tid];
                osc[r] = ssc[tid];
                obb[r * 4 + 0] = sx1[tid];
                obb[r * 4 + 1] = sy1[tid];
                obb[r * 4 + 2] = sx2[tid];
                obb[r * 4 + 3] = sy2[tid];
            }
        }
    }
    __syncthreads();
    if (tid < POST) {
        out[b * POST + tid]       = oid[tid];
        out[800 + b * POST + tid] = osc[tid];
    }
    if (tid < POST * 4) out[1600 + b * POST * 4 + tid] = obb[tid];
}

// ---------------------------------------------------------------------------
extern "C" void kernel_launch(void* const* d_in, const int* in_sizes, int n_in,
                              void* d_out, int out_size, void* d_ws, size_t ws_size,
                              hipStream_t stream)
{
    const float* tip0 = (const float*)d_in[0];
    const float* tip1 = (const float*)d_in[1];
    const float* tip2 = (const float*)d_in[2];
    const float* anc0 = (const float*)d_in[3];
    const float* anc1 = (const float*)d_in[4];
    const float* anc2 = (const float*)d_in[5];
    float* out = (float*)d_out;

    // ws: hist(8*2048) | cutb(8) | ccnt(8) | flags(8) | ckey(8*CAP) | cidx(8*CAP)
    unsigned* hist  = (unsigned*)d_ws;
    unsigned* cutb  = hist + 8 * NBIN1;
    unsigned* ccnt  = cutb + 8;
    unsigned* flags = ccnt + 8;
    unsigned* ckey  = flags + 8;
    unsigned* cidx  = ckey + (size_t)8 * CAP;

    init_kernel<<<(NBIN1 * 8 + 24 + 255) / 256, 256, 0, stream>>>(hist);

    dim3 g(10, 10, 24);
    score_main<<<g, 256, 0, stream>>>(tip0, tip1, tip2, ccnt, ckey, cidx);
    validate_kernel<<<1, 64, 0, stream>>>(ccnt, flags);
    fb_hist<<<g, 256, 0, stream>>>(tip0, tip1, tip2, hist, flags);
    fb_cut<<<8, 256, 0, stream>>>(hist, cutb, flags);
    fb_compact<<<g, 256, 0, stream>>>(tip0, tip1, tip2, cutb, ccnt, ckey, cidx, flags);
    nms_kernel<<<8, 512, 0, stream>>>(tip0, tip1, tip2, anc0, anc1, anc2,
                                      ckey, cidx, ccnt, out);
}

// Round 10
// 220.499 us; speedup vs baseline: 9.0911x; 1.2257x over previous
//
#include <hip/hip_runtime.h>
#include <stdint.h>

#define NUMA 3
#define NUMC 80
#define CAP  49152
#define CAP2 8192
#define KTOP 400
#define POST 100
#define NBIN1 2048
#define EQCAP 1024
#define KEY0 0x3EE66666u   // __float_as_uint(0.45f): static compact threshold
#define LBUF 2048          // per-block LDS candidate buffer

typedef float f32x4 __attribute__((ext_vector_type(4)));

__device__ __forceinline__ float sigmoidf_(float x) { return 1.0f / (1.0f + expf(-x)); }
__device__ __forceinline__ unsigned uminu(unsigned a, unsigned b) { return a < b ? a : b; }

// ---------------- init: zero histN + histF + counters ----------------------
__global__ void init_kernel(unsigned* __restrict__ p) {
    int i = blockIdx.x * blockDim.x + threadIdx.x;
    if (i < NBIN1 * 16 + 40) p[i] = 0;
}

// ---------------- main pass: decode + LDS compact + fine histogram ---------
// grid (10, 10, 24): x = hw-chunk (0-1: t0 scalar; 2-3: t1 vec; 4-9: t2 vec),
// y = class-group (8 classes), z = b*3 + a.  (R9-verified structure + lhist.)
__global__ __launch_bounds__(256) void score_main(
        const float* __restrict__ t0, const float* __restrict__ t1,
        const float* __restrict__ t2,
        unsigned* __restrict__ ccnt, unsigned* __restrict__ ckey,
        unsigned* __restrict__ cidx, unsigned* __restrict__ histN)
{
    __shared__ unsigned lkey[LBUF], lidx[LBUF];
    __shared__ unsigned lh[NBIN1];
    __shared__ unsigned lcnt, lbase;
    const int tid = threadIdx.x;
    if (tid == 0) lcnt = 0;
    for (int i = tid; i < NBIN1; i += 256) lh[i] = 0;
    __syncthreads();

    const int ba = blockIdx.z;
    const int b = ba / 3, a = ba - 3 * b;
    const int c0 = blockIdx.y * 8;
    const int cx = blockIdx.x;

    #define LEMIT(SC, IDX) do { \
        unsigned key_ = __float_as_uint(SC); \
        if (key_ >= KEY0) { \
            atomicAdd(&lh[(key_ - KEY0) >> 13], 1u); \
            unsigned pos_ = atomicAdd(&lcnt, 1u); \
            if (pos_ < LBUF) { lkey[pos_] = key_; lidx[pos_] = (IDX); } \
        } \
    } while (0)

    if (cx < 2) {
        // ---- t0: HW=361, scalar (plane stride not 16B-aligned) ----
        const int hw = cx * 256 + tid;
        if (hw < 361) {
            const float* base = t0 + (size_t)(b * 255 + a * 85) * 361;
            float cr = base[4 * 361 + hw];
            const float* p0 = base + (size_t)(5 + c0) * 361 + hw;
            float x0 = p0[0 * 361], x1 = p0[1 * 361], x2 = p0[2 * 361], x3 = p0[3 * 361];
            float x4 = p0[4 * 361], x5 = p0[5 * 361], x6 = p0[6 * 361], x7 = p0[7 * 361];
            float cf = sigmoidf_(cr);
            unsigned ib = (unsigned)((hw * NUMA + a) * NUMC + c0);
            LEMIT(sigmoidf_(x0) * cf, ib + 0);
            LEMIT(sigmoidf_(x1) * cf, ib + 1);
            LEMIT(sigmoidf_(x2) * cf, ib + 2);
            LEMIT(sigmoidf_(x3) * cf, ib + 3);
            LEMIT(sigmoidf_(x4) * cf, ib + 4);
            LEMIT(sigmoidf_(x5) * cf, ib + 5);
            LEMIT(sigmoidf_(x6) * cf, ib + 6);
            LEMIT(sigmoidf_(x7) * cf, ib + 7);
        }
    } else {
        // ---- t1/t2: float4 ----
        const float* tip; int vHW, v, candOff;
        if (cx < 4) { tip = t1; vHW = 361;  v = (cx - 2) * 256 + tid; candOff = 86640; }
        else        { tip = t2; vHW = 1444; v = (cx - 4) * 256 + tid; candOff = 433200; }
        if (v < vHW) {
            const f32x4* bp = (const f32x4*)(tip + (size_t)(b * 255 + a * 85) * (size_t)(vHW * 4));
            f32x4 cv = bp[(size_t)4 * vHW + v];
            const f32x4* p0 = bp + (size_t)(5 + c0) * vHW + v;
            f32x4 s0 = p0[0 * (size_t)vHW], s1 = p0[1 * (size_t)vHW];
            f32x4 s2 = p0[2 * (size_t)vHW], s3 = p0[3 * (size_t)vHW];
            f32x4 s4 = p0[4 * (size_t)vHW], s5 = p0[5 * (size_t)vHW];
            f32x4 s6 = p0[6 * (size_t)vHW], s7 = p0[7 * (size_t)vHW];
            float cf0 = sigmoidf_(cv[0]), cf1 = sigmoidf_(cv[1]);
            float cf2 = sigmoidf_(cv[2]), cf3 = sigmoidf_(cv[3]);
            unsigned ib0 = (unsigned)(candOff + (v * 4 * NUMA + a) * NUMC + c0);
            #define EMIT4(S, U) do { \
                unsigned ib = ib0 + (U); \
                LEMIT(sigmoidf_((S)[0]) * cf0, ib); \
                LEMIT(sigmoidf_((S)[1]) * cf1, ib + 240); \
                LEMIT(sigmoidf_((S)[2]) * cf2, ib + 480); \
                LEMIT(sigmoidf_((S)[3]) * cf3, ib + 720); \
            } while (0)
            EMIT4(s0, 0); EMIT4(s1, 1); EMIT4(s2, 2); EMIT4(s3, 3);
            EMIT4(s4, 4); EMIT4(s5, 5); EMIT4(s6, 6); EMIT4(s7, 7);
            #undef EMIT4
        }
    }
    #undef LEMIT

    __syncthreads();
    if (tid == 0) {
        unsigned c = lcnt;
        if (c > LBUF) {
            atomicOr(&ccnt[b], 0x80000000u);   // force invalid -> exact fallback
            lbase = 0xFFFFFFFFu;
        } else {
            lbase = atomicAdd(&ccnt[b], c);
        }
    }
    __syncthreads();
    unsigned c = uminu(lcnt, (unsigned)LBUF);
    unsigned basep = lbase;
    if (basep != 0xFFFFFFFFu) {
        for (unsigned i = tid; i < c; i += 256) {
            unsigned p = basep + i;
            if (p < CAP) {
                ckey[(size_t)b * CAP + p] = lkey[i];
                cidx[(size_t)b * CAP + p] = lidx[i];
            }
        }
    }
    unsigned* gh = histN + b * NBIN1;
    for (int i = tid; i < NBIN1; i += 256) {
        unsigned v2 = lh[i];
        if (v2) atomicAdd(&gh[i], v2);
    }
}

// ---------------- wave-parallel rank select over an LDS histogram ----------
__device__ __forceinline__ void wave_select(const unsigned* h, int nbins, unsigned rank,
                                            unsigned* resv, int tid)
{
    if (tid >= 64) return;
    const int lane = tid;
    const int cs = nbins >> 6;
    unsigned v = 0;
    for (int k = 0; k < cs; k++) {
        int off = (k + lane) & (cs - 1);
        v += h[lane * cs + off];
    }
    unsigned S = v;
    #pragma unroll
    for (int o = 1; o < 64; o <<= 1) {
        unsigned t = (unsigned)__shfl_down((int)S, o);
        if (lane + o < 64) S += t;
    }
    unsigned long long bm = __ballot(S >= rank);
    if (bm == 0ull) bm = 1ull;   // safety: rank > total
    int C = 63 - __builtin_clzll(bm);
    unsigned SC = (unsigned)__builtin_amdgcn_readlane((int)S, C);
    unsigned vC = (unsigned)__builtin_amdgcn_readlane((int)v, C);
    unsigned rem = rank - (SC - vC);
    unsigned w = (lane < cs) ? h[C * cs + lane] : 0u;
    unsigned T = w;
    #pragma unroll
    for (int o = 1; o < 64; o <<= 1) {
        unsigned t = (unsigned)__shfl_down((int)T, o);
        if (lane + o < 64) T += t;
    }
    unsigned long long bm2 = __ballot((T >= rem) && (lane < cs));
    if (bm2 == 0ull) bm2 = 1ull;
    int B = 63 - __builtin_clzll(bm2);
    unsigned TB = (unsigned)__builtin_amdgcn_readlane((int)T, B);
    unsigned wB = (unsigned)__builtin_amdgcn_readlane((int)w, B);
    if (lane == 0) {
        resv[0] = (unsigned)(C * cs + B);
        resv[1] = rem - (TB - wB);
    }
}

// ---------------- findcut_v: validate static cut + rank-400 floor ----------
__global__ __launch_bounds__(256) void findcut_v(const unsigned* __restrict__ histN,
                                                 unsigned* __restrict__ cutfloor,
                                                 unsigned* __restrict__ ccnt,
                                                 unsigned* __restrict__ flags) {
    __shared__ unsigned h[NBIN1];
    __shared__ unsigned resv[2];
    int b = blockIdx.x;
    for (int i = threadIdx.x; i < NBIN1; i += 256) h[i] = histN[b * NBIN1 + i];
    __syncthreads();
    wave_select(h, NBIN1, KTOP, resv, threadIdx.x);
    __syncthreads();
    if (threadIdx.x == 0) {
        unsigned c = ccnt[b];
        bool ok = (c >= KTOP) && (c <= CAP);
        flags[b] = ok ? 1u : 0u;
        if (ok) {
            cutfloor[b] = KEY0 + (resv[0] << 13);
        } else {
            cutfloor[b] = 0u;
            ccnt[b] = 0;
        }
    }
}

// ---------------- fallback: full histogram (early-exits when valid) --------
__global__ __launch_bounds__(256) void fb_hist(
        const float* __restrict__ t0, const float* __restrict__ t1,
        const float* __restrict__ t2,
        unsigned* __restrict__ histF, const unsigned* __restrict__ flags)
{
    const int ba = blockIdx.z;
    const int b = ba / 3, a = ba - 3 * b;
    if (flags[b]) return;
    __shared__ unsigned lh[NBIN1];
    const int tid = threadIdx.x;
    for (int i = tid; i < NBIN1; i += 256) lh[i] = 0;
    __syncthreads();
    const int c0 = blockIdx.y * 8;
    const int cx = blockIdx.x;
    if (cx < 2) {
        const int hw = cx * 256 + tid;
        if (hw < 361) {
            const float* base = t0 + (size_t)(b * 255 + a * 85) * 361;
            float cf = sigmoidf_(base[4 * 361 + hw]);
            for (int u = 0; u < 8; u++) {
                float sc = sigmoidf_(base[(size_t)(5 + c0 + u) * 361 + hw]) * cf;
                atomicAdd(&lh[__float_as_uint(sc) >> 19], 1u);
            }
        }
    } else {
        const float* tip; int vHW, v;
        if (cx < 4) { tip = t1; vHW = 361;  v = (cx - 2) * 256 + tid; }
        else        { tip = t2; vHW = 1444; v = (cx - 4) * 256 + tid; }
        if (v < vHW) {
            const f32x4* bp = (const f32x4*)(tip + (size_t)(b * 255 + a * 85) * (size_t)(vHW * 4));
            f32x4 cv = bp[(size_t)4 * vHW + v];
            float cf[4] = { sigmoidf_(cv[0]), sigmoidf_(cv[1]), sigmoidf_(cv[2]), sigmoidf_(cv[3]) };
            for (int u = 0; u < 8; u++) {
                f32x4 s = bp[(size_t)(5 + c0 + u) * vHW + v];
                for (int l = 0; l < 4; l++)
                    atomicAdd(&lh[__float_as_uint(sigmoidf_(s[l]) * cf[l]) >> 19], 1u);
            }
        }
    }
    __syncthreads();
    unsigned* gh = histF + b * NBIN1;
    for (int i = tid; i < NBIN1; i += 256) {
        unsigned v2 = lh[i];
        if (v2) atomicAdd(&gh[i], v2);
    }
}

// ---------------- fallback: find rank-400 bin (coarse) ---------------------
__global__ __launch_bounds__(256) void fb_cut(const unsigned* __restrict__ histF,
                                              unsigned* __restrict__ cutb,
                                              const unsigned* __restrict__ flags) {
    int b = blockIdx.x;
    if (flags[b]) return;
    __shared__ unsigned h[NBIN1];
    __shared__ unsigned resv[2];
    for (int i = threadIdx.x; i < NBIN1; i += 256) h[i] = histF[b * NBIN1 + i];
    __syncthreads();
    wave_select(h, NBIN1, KTOP, resv, threadIdx.x);
    __syncthreads();
    if (threadIdx.x == 0) cutb[b] = resv[0];
}

// ---------------- fallback: recompact with exact bin cut -------------------
__global__ __launch_bounds__(256) void fb_compact(
        const float* __restrict__ t0, const float* __restrict__ t1,
        const float* __restrict__ t2,
        const unsigned* __restrict__ cutb, unsigned* __restrict__ ccnt,
        unsigned* __restrict__ ckey, unsigned* __restrict__ cidx,
        const unsigned* __restrict__ flags)
{
    const int ba = blockIdx.z;
    const int b = ba / 3, a = ba - 3 * b;
    if (flags[b]) return;
    const int tid = threadIdx.x;
    const int c0 = blockIdx.y * 8;
    const int cx = blockIdx.x;
    unsigned cutkey = cutb[b] << 19;

    if (cx < 2) {
        const int hw = cx * 256 + tid;
        if (hw < 361) {
            const float* base = t0 + (size_t)(b * 255 + a * 85) * 361;
            float cf = sigmoidf_(base[4 * 361 + hw]);
            for (int u = 0; u < 8; u++) {
                float sc = sigmoidf_(base[(size_t)(5 + c0 + u) * 361 + hw]) * cf;
                unsigned key = __float_as_uint(sc);
                if (key >= cutkey) {
                    unsigned pos = atomicAdd(&ccnt[b], 1u);
                    if (pos < CAP) {
                        ckey[(size_t)b * CAP + pos] = key;
                        cidx[(size_t)b * CAP + pos] = (unsigned)((hw * NUMA + a) * NUMC + c0 + u);
                    }
                }
            }
        }
    } else {
        const float* tip; int vHW, v, candOff;
        if (cx < 4) { tip = t1; vHW = 361;  v = (cx - 2) * 256 + tid; candOff = 86640; }
        else        { tip = t2; vHW = 1444; v = (cx - 4) * 256 + tid; candOff = 433200; }
        if (v < vHW) {
            const f32x4* bp = (const f32x4*)(tip + (size_t)(b * 255 + a * 85) * (size_t)(vHW * 4));
            f32x4 cv = bp[(size_t)4 * vHW + v];
            float cf[4] = { sigmoidf_(cv[0]), sigmoidf_(cv[1]), sigmoidf_(cv[2]), sigmoidf_(cv[3]) };
            unsigned ib0 = (unsigned)(candOff + (v * 4 * NUMA + a) * NUMC + c0);
            for (int u = 0; u < 8; u++) {
                f32x4 s = bp[(size_t)(5 + c0 + u) * vHW + v];
                for (int l = 0; l < 4; l++) {
                    float sc = sigmoidf_(s[l]) * cf[l];
                    unsigned key = __float_as_uint(sc);
                    if (key >= cutkey) {
                        unsigned pos = atomicAdd(&ccnt[b], 1u);
                        if (pos < CAP) {
                            ckey[(size_t)b * CAP + pos] = key;
                            cidx[(size_t)b * CAP + pos] = ib0 + (unsigned)u + (unsigned)l * 240;
                        }
                    }
                }
            }
        }
    }
}

// ---------------- prefilter: keys >= cutfloor into small buffer ------------
// grid (32, 1, 8): 32 chunks per image. Per-block filtered count provably
// <= ceil(CAP/8192)*256 = 1536 < LBUF.
__global__ __launch_bounds__(256) void prefilter(
        const unsigned* __restrict__ ckey, const unsigned* __restrict__ cidx,
        const unsigned* __restrict__ ccnt, const unsigned* __restrict__ cutfloor,
        unsigned* __restrict__ cnt2, unsigned* __restrict__ ckey2,
        unsigned* __restrict__ cidx2)
{
    __shared__ unsigned lk[LBUF], li[LBUF];
    __shared__ unsigned lcnt, lbase;
    const int tid = threadIdx.x;
    const int b = blockIdx.z;
    if (tid == 0) lcnt = 0;
    __syncthreads();
    const unsigned n = uminu(ccnt[b], (unsigned)CAP);
    const unsigned cutf = cutfloor[b];
    const unsigned* ck = ckey + (size_t)b * CAP;
    const unsigned* ci = cidx + (size_t)b * CAP;
    for (unsigned i = blockIdx.x * 256 + tid; i < n; i += 32 * 256) {
        unsigned k = ck[i];
        if (k >= cutf) {
            unsigned p = atomicAdd(&lcnt, 1u);
            if (p < LBUF) { lk[p] = k; li[p] = ci[i]; }
        }
    }
    __syncthreads();
    if (tid == 0) lbase = atomicAdd(&cnt2[b], uminu(lcnt, (unsigned)LBUF));
    __syncthreads();
    unsigned c = uminu(lcnt, (unsigned)LBUF);
    for (unsigned i = tid; i < c; i += 256) {
        unsigned p = lbase + i;
        if (p < CAP2) {
            ckey2[(size_t)b * CAP2 + p] = lk[i];
            cidx2[(size_t)b * CAP2 + p] = li[i];
        }
    }
}

// ---------------- per-image: exact top-400, NMS, output --------------------
__global__ __launch_bounds__(512) void nms_kernel(
        const float* __restrict__ t0, const float* __restrict__ t1,
        const float* __restrict__ t2,
        const float* __restrict__ anc0, const float* __restrict__ anc1,
        const float* __restrict__ anc2,
        const unsigned* __restrict__ ckey, const unsigned* __restrict__ cidx,
        const unsigned* __restrict__ ccnt,
        const unsigned* __restrict__ ckey2, const unsigned* __restrict__ cidx2,
        const unsigned* __restrict__ cnt2, float* __restrict__ out)
{
    const int b = blockIdx.x;
    const int tid = threadIdx.x;
    const int T = 512;

    __shared__ unsigned hist[4096];
    __shared__ unsigned resv[2];
    __shared__ unsigned selk[512], seli[512];
    __shared__ unsigned eqi[EQCAP];
    __shared__ float sx1[KTOP], sy1[KTOP], sx2[KTOP], sy2[KTOP], ssc[KTOP];
    __shared__ int   scid[KTOP];
    __shared__ unsigned long long maskS[KTOP * 7];
    __shared__ unsigned long long vkeep[7];
    __shared__ unsigned cnts[2];
    __shared__ float oid[POST], osc[POST], obb[POST * 4];

    // prefer the prefiltered list; fall back to the full list on overflow
    unsigned n2 = cnt2[b];
    const unsigned* ck; const unsigned* ci; unsigned n;
    if (n2 <= (unsigned)CAP2) {
        ck = ckey2 + (size_t)b * CAP2; ci = cidx2 + (size_t)b * CAP2; n = n2;
    } else {
        ck = ckey + (size_t)b * CAP; ci = cidx + (size_t)b * CAP;
        n = uminu(ccnt[b], (unsigned)CAP);
    }

    // ---- Round 1: bits [30:19] ----
    for (int i = tid; i < NBIN1; i += T) hist[i] = 0;
    __syncthreads();
    for (unsigned i = tid; i < n; i += T) atomicAdd(&hist[ck[i] >> 19], 1u);
    __syncthreads();
    wave_select(hist, NBIN1, KTOP, resv, tid);
    __syncthreads();
    unsigned b1 = resv[0], r2 = resv[1];
    __syncthreads();

    // ---- Round 2: bits [18:7] ----
    for (int i = tid; i < 4096; i += T) hist[i] = 0;
    __syncthreads();
    for (unsigned i = tid; i < n; i += T) {
        unsigned k = ck[i];
        if ((k >> 19) == b1) atomicAdd(&hist[(k >> 7) & 0xFFFu], 1u);
    }
    __syncthreads();
    wave_select(hist, 4096, r2, resv, tid);
    __syncthreads();
    unsigned b2 = resv[0], r3 = resv[1];
    __syncthreads();

    // ---- Round 3: bits [6:0] ----
    for (int i = tid; i < 128; i += T) hist[i] = 0;
    __syncthreads();
    unsigned pref = (b1 << 12) | b2;
    for (unsigned i = tid; i < n; i += T) {
        unsigned k = ck[i];
        if ((k >> 7) == pref) atomicAdd(&hist[k & 127u], 1u);
    }
    __syncthreads();
    wave_select(hist, 128, r3, resv, tid);
    __syncthreads();
    unsigned b3 = resv[0], needEq = resv[1];
    unsigned K400 = (b1 << 19) | (b2 << 7) | b3;
    __syncthreads();

    // ---- compaction ----
    selk[tid] = 0u; seli[tid] = 0xFFFFFFFFu;
    for (int i = tid; i < EQCAP; i += T) eqi[i] = 0xFFFFFFFFu;
    if (tid == 0) { cnts[0] = 0; cnts[1] = 0; }
    __syncthreads();
    for (unsigned i = tid; i < n; i += T) {
        unsigned k = ck[i];
        if (k > K400) {
            unsigned p = atomicAdd(&cnts[0], 1u);
            if (p < KTOP) { selk[p] = k; seli[p] = ci[i]; }
        } else if (k == K400) {
            unsigned q = atomicAdd(&cnts[1], 1u);
            if (q < EQCAP) eqi[q] = ci[i];
        }
    }
    __syncthreads();
    unsigned selCnt = uminu(cnts[0], (unsigned)KTOP);
    unsigned eqN   = uminu(cnts[1], (unsigned)EQCAP);

    // ---- tie list: only sort if we must pick a strict subset ----
    if (eqN > needEq) {
        int P2 = 1; while ((unsigned)P2 < eqN) P2 <<= 1;
        for (int k2 = 2; k2 <= P2; k2 <<= 1) {
            for (int j = k2 >> 1; j > 0; j >>= 1) {
                __syncthreads();
                for (int i = tid; i < P2; i += T) {
                    int ixj = i ^ j;
                    if (ixj > i && ixj < P2) {
                        unsigned va = eqi[i], vb = eqi[ixj];
                        bool up = ((i & k2) == 0);
                        if (up ? (va > vb) : (va < vb)) { eqi[i] = vb; eqi[ixj] = va; }
                    }
                }
            }
        }
        __syncthreads();
    }
    for (unsigned t2v = tid; t2v < needEq; t2v += T) {
        unsigned p = selCnt + t2v;
        if (p < KTOP) { selk[p] = K400; seli[p] = eqi[t2v]; }
    }
    __syncthreads();

    // ---- bitonic sort 512 by (key desc, idx asc); j<64 passes in-wave ----
    for (int k2 = 2; k2 <= 512; k2 <<= 1) {
        int j = k2 >> 1;
        for (; j >= 64; j >>= 1) {
            __syncthreads();
            int i = tid, ixj = i ^ j;
            if (ixj > i) {
                unsigned ka = selk[i], kb = selk[ixj], ia = seli[i], ib = seli[ixj];
                bool before = (ka > kb) || (ka == kb && ia < ib);
                bool up = ((i & k2) == 0);
                if (up ? !before : before) {
                    selk[i] = kb; selk[ixj] = ka; seli[i] = ib; seli[ixj] = ia;
                }
            }
        }
        __syncthreads();
        for (; j > 0; j >>= 1) {
            int i = tid, ixj = i ^ j;
            if (ixj > i) {
                unsigned ka = selk[i], kb = selk[ixj], ia = seli[i], ib = seli[ixj];
                bool before = (ka > kb) || (ka == kb && ia < ib);
                bool up = ((i & k2) == 0);
                if (up ? !before : before) {
                    selk[i] = kb; selk[ixj] = ka; seli[i] = ib; seli[ixj] = ia;
                }
            }
        }
    }
    __syncthreads();

    // ---- gather + on-the-fly box decode for the 400 selected ----
    if (tid < KTOP) {
        unsigned idx = seli[tid];
        const float* tip; const float* anc; int HW, W, candOff; float strideF;
        if (idx < 86640u)       { tip = t0; anc = anc0; HW = 361;  W = 19; strideF = 32.f; candOff = 0; }
        else if (idx < 433200u) { tip = t1; anc = anc1; HW = 1444; W = 38; strideF = 16.f; candOff = 86640; }
        else                    { tip = t2; anc = anc2; HW = 5776; W = 76; strideF = 8.f;  candOff = 433200; }
        unsigned local = idx - (unsigned)candOff;
        int cls = (int)(local % NUMC);
        int nn  = (int)(local / NUMC);
        int a = nn % NUMA, hwl = nn / NUMA;
        const float* base = tip + (size_t)(b * 255 + a * 85) * HW + hwl;
        float tx = base[0];
        float ty = base[(size_t)HW];
        float tw = base[(size_t)2 * HW];
        float th = base[(size_t)3 * HW];
        float fx = (float)(hwl % W), fy = (float)(hwl / W);
        float cx = (sigmoidf_(tx) + fx) * strideF;
        float cy = (sigmoidf_(ty) + fy) * strideF;
        float hw_ = expf(tw) * anc[2 * a]     * 0.5f;
        float hh_ = expf(th) * anc[2 * a + 1] * 0.5f;
        sx1[tid] = cx - hw_; sy1[tid] = cy - hh_;
        sx2[tid] = cx + hw_; sy2[tid] = cy + hh_;
        ssc[tid] = __uint_as_float(selk[tid]);
        scid[tid] = cls;
    }
    __syncthreads();

    // ---- suppression bitmasks ----
    for (int p = tid; p < KTOP * 7; p += T) {
        int i = p / 7, w = p - i * 7;
        float x1i = sx1[i], y1i = sy1[i], x2i = sx2[i], y2i = sy2[i];
        float ai = fmaxf(x2i - x1i, 0.f) * fmaxf(y2i - y1i, 0.f);
        int cidI = scid[i];
        unsigned long long m = 0ull;
        int j0 = w * 64;
        int j1 = j0 + 64; if (j1 > KTOP) j1 = KTOP;
        int js = j0 > i + 1 ? j0 : i + 1;
        for (int j = js; j < j1; j++) {
            if (scid[j] != cidI) continue;
            float iw = fminf(x2i, sx2[j]) - fmaxf(x1i, sx1[j]);
            float ih = fminf(y2i, sy2[j]) - fmaxf(y1i, sy1[j]);
            iw = fmaxf(iw, 0.f); ih = fmaxf(ih, 0.f);
            float inter = iw * ih;
            float aj = fmaxf(sx2[j] - sx1[j], 0.f) * fmaxf(sy2[j] - sy1[j], 0.f);
            float iou = inter / (ai + aj - inter + 1e-12f);
            if (iou > 0.45f) m |= (1ull << (j - j0));
        }
        maskS[p] = m;
    }
    __syncthreads();

    // ---- greedy NMS: keep words in lanes 0..6; v_readlane broadcast -------
    if (tid < 64) {
        unsigned long long keep = 0ull;
        if (tid < 7) keep = (tid == 6) ? 0xFFFFull : ~0ull;
        unsigned long long m = (tid < 7) ? maskS[tid] : 0ull;
        for (int i = 0; i < KTOP; i++) {
            unsigned long long mn = (tid < 7 && i + 1 < KTOP) ? maskS[(i + 1) * 7 + tid] : 0ull;
            int w = i >> 6;
            unsigned klo = (unsigned)__builtin_amdgcn_readlane((int)(unsigned)(keep & 0xFFFFFFFFull), w);
            unsigned khi = (unsigned)__builtin_amdgcn_readlane((int)(unsigned)(keep >> 32), w);
            unsigned long long kw = ((unsigned long long)khi << 32) | klo;
            if ((kw >> (i & 63)) & 1ull) keep &= ~m;
            m = mn;
        }
        if (tid < 7) vkeep[tid] = keep;
    }
    __syncthreads();

    // ---- emit top-100, pad -1 ----
    if (tid < POST) { oid[tid] = -1.f; osc[tid] = -1.f; }
    if (tid < POST * 4) obb[tid] = -1.f;
    __syncthreads();
    if (tid < KTOP) {
        int w = tid >> 6, bp = tid & 63;
        unsigned long long kw = vkeep[w];
        if ((kw >> bp) & 1ull) {
            int r = 0;
            for (int q = 0; q < w; q++) r += __popcll(vkeep[q]);
            r += __popcll(kw & ((1ull << bp) - 1ull));
            if (r < POST) {
                oid[r] = (float)scid[tid];
                osc[r] = ssc[tid];
                obb[r * 4 + 0] = sx1[tid];
                obb[r * 4 + 1] = sy1[tid];
                obb[r * 4 + 2] = sx2[tid];
                obb[r * 4 + 3] = sy2[tid];
            }
        }
    }
    __syncthreads();
    if (tid < POST) {
        out[b * POST + tid]       = oid[tid];
        out[800 + b * POST + tid] = osc[tid];
    }
    if (tid < POST * 4) out[1600 + b * POST * 4 + tid] = obb[tid];
}

// ---------------------------------------------------------------------------
extern "C" void kernel_launch(void* const* d_in, const int* in_sizes, int n_in,
                              void* d_out, int out_size, void* d_ws, size_t ws_size,
                              hipStream_t stream)
{
    const float* tip0 = (const float*)d_in[0];
    const float* tip1 = (const float*)d_in[1];
    const float* tip2 = (const float*)d_in[2];
    const float* anc0 = (const float*)d_in[3];
    const float* anc1 = (const float*)d_in[4];
    const float* anc2 = (const float*)d_in[5];
    float* out = (float*)d_out;

    // ws: histN(8*2048) | histF(8*2048) | cutb(8) | cutfloor(8) | ccnt(8) |
    //     cnt2(8) | flags(8) | ckey(8*CAP) | cidx(8*CAP) | ckey2(8*CAP2) | cidx2(8*CAP2)
    unsigned* histN    = (unsigned*)d_ws;
    unsigned* histF    = histN + 8 * NBIN1;
    unsigned* cutb     = histF + 8 * NBIN1;
    unsigned* cutfloor = cutb + 8;
    unsigned* ccnt     = cutfloor + 8;
    unsigned* cnt2     = ccnt + 8;
    unsigned* flags    = cnt2 + 8;
    unsigned* ckey     = flags + 8;
    unsigned* cidx     = ckey + (size_t)8 * CAP;
    unsigned* ckey2    = cidx + (size_t)8 * CAP;
    unsigned* cidx2    = ckey2 + (size_t)8 * CAP2;

    init_kernel<<<(NBIN1 * 16 + 40 + 255) / 256, 256, 0, stream>>>(histN);

    dim3 g(10, 10, 24);
    score_main<<<g, 256, 0, stream>>>(tip0, tip1, tip2, ccnt, ckey, cidx, histN);
    findcut_v<<<8, 256, 0, stream>>>(histN, cutfloor, ccnt, flags);
    fb_hist<<<g, 256, 0, stream>>>(tip0, tip1, tip2, histF, flags);
    fb_cut<<<8, 256, 0, stream>>>(histF, cutb, flags);
    fb_compact<<<g, 256, 0, stream>>>(tip0, tip1, tip2, cutb, ccnt, ckey, cidx, flags);
    prefilter<<<dim3(32, 1, 8), 256, 0, stream>>>(ckey, cidx, ccnt, cutfloor,
                                                  cnt2, ckey2, cidx2);
    nms_kernel<<<8, 512, 0, stream>>>(tip0, tip1, tip2, anc0, anc1, anc2,
                                      ckey, cidx, ccnt, ckey2, cidx2, cnt2, out);
}

// Round 11
// 195.913 us; speedup vs baseline: 10.2319x; 1.1255x over previous
//
#include <hip/hip_runtime.h>
#include <stdint.h>

#define NUMA 3
#define NUMC 80
#define CAP  49152
#define CAP2 8192
#define KTOP 400
#define POST 100
#define NBIN1 2048
#define EQCAP 1024
#define KEY0 0x3EE66666u   // __float_as_uint(0.45f): static compact threshold
#define LBUF 2048          // per-block LDS candidate buffer
#define NMASK (KTOP * 7)   // 2800 mask words per image

typedef float f32x4 __attribute__((ext_vector_type(4)));

__device__ __forceinline__ float sigmoidf_(float x) { return 1.0f / (1.0f + expf(-x)); }
__device__ __forceinline__ unsigned uminu(unsigned a, unsigned b) { return a < b ? a : b; }

// ---------------- init: zero histN + histF + counters ----------------------
__global__ void init_kernel(unsigned* __restrict__ p) {
    int i = blockIdx.x * blockDim.x + threadIdx.x;
    if (i < NBIN1 * 16 + 40) p[i] = 0;
}

// ---------------- main pass: decode + LDS compact + fine histogram ---------
__global__ __launch_bounds__(256) void score_main(
        const float* __restrict__ t0, const float* __restrict__ t1,
        const float* __restrict__ t2,
        unsigned* __restrict__ ccnt, unsigned* __restrict__ ckey,
        unsigned* __restrict__ cidx, unsigned* __restrict__ histN)
{
    __shared__ unsigned lkey[LBUF], lidx[LBUF];
    __shared__ unsigned lh[NBIN1];
    __shared__ unsigned lcnt, lbase;
    const int tid = threadIdx.x;
    if (tid == 0) lcnt = 0;
    for (int i = tid; i < NBIN1; i += 256) lh[i] = 0;
    __syncthreads();

    const int ba = blockIdx.z;
    const int b = ba / 3, a = ba - 3 * b;
    const int c0 = blockIdx.y * 8;
    const int cx = blockIdx.x;

    #define LEMIT(SC, IDX) do { \
        unsigned key_ = __float_as_uint(SC); \
        if (key_ >= KEY0) { \
            atomicAdd(&lh[(key_ - KEY0) >> 13], 1u); \
            unsigned pos_ = atomicAdd(&lcnt, 1u); \
            if (pos_ < LBUF) { lkey[pos_] = key_; lidx[pos_] = (IDX); } \
        } \
    } while (0)

    if (cx < 2) {
        const int hw = cx * 256 + tid;
        if (hw < 361) {
            const float* base = t0 + (size_t)(b * 255 + a * 85) * 361;
            float cr = base[4 * 361 + hw];
            const float* p0 = base + (size_t)(5 + c0) * 361 + hw;
            float x0 = p0[0 * 361], x1 = p0[1 * 361], x2 = p0[2 * 361], x3 = p0[3 * 361];
            float x4 = p0[4 * 361], x5 = p0[5 * 361], x6 = p0[6 * 361], x7 = p0[7 * 361];
            float cf = sigmoidf_(cr);
            unsigned ib = (unsigned)((hw * NUMA + a) * NUMC + c0);
            LEMIT(sigmoidf_(x0) * cf, ib + 0);
            LEMIT(sigmoidf_(x1) * cf, ib + 1);
            LEMIT(sigmoidf_(x2) * cf, ib + 2);
            LEMIT(sigmoidf_(x3) * cf, ib + 3);
            LEMIT(sigmoidf_(x4) * cf, ib + 4);
            LEMIT(sigmoidf_(x5) * cf, ib + 5);
            LEMIT(sigmoidf_(x6) * cf, ib + 6);
            LEMIT(sigmoidf_(x7) * cf, ib + 7);
        }
    } else {
        const float* tip; int vHW, v, candOff;
        if (cx < 4) { tip = t1; vHW = 361;  v = (cx - 2) * 256 + tid; candOff = 86640; }
        else        { tip = t2; vHW = 1444; v = (cx - 4) * 256 + tid; candOff = 433200; }
        if (v < vHW) {
            const f32x4* bp = (const f32x4*)(tip + (size_t)(b * 255 + a * 85) * (size_t)(vHW * 4));
            f32x4 cv = bp[(size_t)4 * vHW + v];
            const f32x4* p0 = bp + (size_t)(5 + c0) * vHW + v;
            f32x4 s0 = p0[0 * (size_t)vHW], s1 = p0[1 * (size_t)vHW];
            f32x4 s2 = p0[2 * (size_t)vHW], s3 = p0[3 * (size_t)vHW];
            f32x4 s4 = p0[4 * (size_t)vHW], s5 = p0[5 * (size_t)vHW];
            f32x4 s6 = p0[6 * (size_t)vHW], s7 = p0[7 * (size_t)vHW];
            float cf0 = sigmoidf_(cv[0]), cf1 = sigmoidf_(cv[1]);
            float cf2 = sigmoidf_(cv[2]), cf3 = sigmoidf_(cv[3]);
            unsigned ib0 = (unsigned)(candOff + (v * 4 * NUMA + a) * NUMC + c0);
            #define EMIT4(S, U) do { \
                unsigned ib = ib0 + (U); \
                LEMIT(sigmoidf_((S)[0]) * cf0, ib); \
                LEMIT(sigmoidf_((S)[1]) * cf1, ib + 240); \
                LEMIT(sigmoidf_((S)[2]) * cf2, ib + 480); \
                LEMIT(sigmoidf_((S)[3]) * cf3, ib + 720); \
            } while (0)
            EMIT4(s0, 0); EMIT4(s1, 1); EMIT4(s2, 2); EMIT4(s3, 3);
            EMIT4(s4, 4); EMIT4(s5, 5); EMIT4(s6, 6); EMIT4(s7, 7);
            #undef EMIT4
        }
    }
    #undef LEMIT

    __syncthreads();
    if (tid == 0) {
        unsigned c = lcnt;
        if (c > LBUF) {
            atomicOr(&ccnt[b], 0x80000000u);
            lbase = 0xFFFFFFFFu;
        } else {
            lbase = atomicAdd(&ccnt[b], c);
        }
    }
    __syncthreads();
    unsigned c = uminu(lcnt, (unsigned)LBUF);
    unsigned basep = lbase;
    if (basep != 0xFFFFFFFFu) {
        for (unsigned i = tid; i < c; i += 256) {
            unsigned p = basep + i;
            if (p < CAP) {
                ckey[(size_t)b * CAP + p] = lkey[i];
                cidx[(size_t)b * CAP + p] = lidx[i];
            }
        }
    }
    unsigned* gh = histN + b * NBIN1;
    for (int i = tid; i < NBIN1; i += 256) {
        unsigned v2 = lh[i];
        if (v2) atomicAdd(&gh[i], v2);
    }
}

// ---------------- wave-parallel rank select over an LDS histogram ----------
__device__ __forceinline__ void wave_select(const unsigned* h, int nbins, unsigned rank,
                                            unsigned* resv, int tid)
{
    if (tid >= 64) return;
    const int lane = tid;
    const int cs = nbins >> 6;
    unsigned v = 0;
    for (int k = 0; k < cs; k++) {
        int off = (k + lane) & (cs - 1);
        v += h[lane * cs + off];
    }
    unsigned S = v;
    #pragma unroll
    for (int o = 1; o < 64; o <<= 1) {
        unsigned t = (unsigned)__shfl_down((int)S, o);
        if (lane + o < 64) S += t;
    }
    unsigned long long bm = __ballot(S >= rank);
    if (bm == 0ull) bm = 1ull;
    int C = 63 - __builtin_clzll(bm);
    unsigned SC = (unsigned)__builtin_amdgcn_readlane((int)S, C);
    unsigned vC = (unsigned)__builtin_amdgcn_readlane((int)v, C);
    unsigned rem = rank - (SC - vC);
    unsigned w = (lane < cs) ? h[C * cs + lane] : 0u;
    unsigned T = w;
    #pragma unroll
    for (int o = 1; o < 64; o <<= 1) {
        unsigned t = (unsigned)__shfl_down((int)T, o);
        if (lane + o < 64) T += t;
    }
    unsigned long long bm2 = __ballot((T >= rem) && (lane < cs));
    if (bm2 == 0ull) bm2 = 1ull;
    int B = 63 - __builtin_clzll(bm2);
    unsigned TB = (unsigned)__builtin_amdgcn_readlane((int)T, B);
    unsigned wB = (unsigned)__builtin_amdgcn_readlane((int)w, B);
    if (lane == 0) {
        resv[0] = (unsigned)(C * cs + B);
        resv[1] = rem - (TB - wB);
    }
}

// ---------------- findcut_v: validate static cut + rank-400 floor ----------
__global__ __launch_bounds__(256) void findcut_v(const unsigned* __restrict__ histN,
                                                 unsigned* __restrict__ cutfloor,
                                                 unsigned* __restrict__ ccnt,
                                                 unsigned* __restrict__ flags) {
    __shared__ unsigned h[NBIN1];
    __shared__ unsigned resv[2];
    int b = blockIdx.x;
    for (int i = threadIdx.x; i < NBIN1; i += 256) h[i] = histN[b * NBIN1 + i];
    __syncthreads();
    wave_select(h, NBIN1, KTOP, resv, threadIdx.x);
    __syncthreads();
    if (threadIdx.x == 0) {
        unsigned c = ccnt[b];
        bool ok = (c >= KTOP) && (c <= CAP);
        flags[b] = ok ? 1u : 0u;
        if (ok) {
            cutfloor[b] = KEY0 + (resv[0] << 13);
        } else {
            cutfloor[b] = 0u;
            ccnt[b] = 0;
        }
    }
}

// ---------------- fallback: full histogram (early-exits when valid) --------
__global__ __launch_bounds__(256) void fb_hist(
        const float* __restrict__ t0, const float* __restrict__ t1,
        const float* __restrict__ t2,
        unsigned* __restrict__ histF, const unsigned* __restrict__ flags)
{
    const int ba = blockIdx.z;
    const int b = ba / 3, a = ba - 3 * b;
    if (flags[b]) return;
    __shared__ unsigned lh[NBIN1];
    const int tid = threadIdx.x;
    for (int i = tid; i < NBIN1; i += 256) lh[i] = 0;
    __syncthreads();
    const int c0 = blockIdx.y * 8;
    const int cx = blockIdx.x;
    if (cx < 2) {
        const int hw = cx * 256 + tid;
        if (hw < 361) {
            const float* base = t0 + (size_t)(b * 255 + a * 85) * 361;
            float cf = sigmoidf_(base[4 * 361 + hw]);
            for (int u = 0; u < 8; u++) {
                float sc = sigmoidf_(base[(size_t)(5 + c0 + u) * 361 + hw]) * cf;
                atomicAdd(&lh[__float_as_uint(sc) >> 19], 1u);
            }
        }
    } else {
        const float* tip; int vHW, v;
        if (cx < 4) { tip = t1; vHW = 361;  v = (cx - 2) * 256 + tid; }
        else        { tip = t2; vHW = 1444; v = (cx - 4) * 256 + tid; }
        if (v < vHW) {
            const f32x4* bp = (const f32x4*)(tip + (size_t)(b * 255 + a * 85) * (size_t)(vHW * 4));
            f32x4 cv = bp[(size_t)4 * vHW + v];
            float cf[4] = { sigmoidf_(cv[0]), sigmoidf_(cv[1]), sigmoidf_(cv[2]), sigmoidf_(cv[3]) };
            for (int u = 0; u < 8; u++) {
                f32x4 s = bp[(size_t)(5 + c0 + u) * vHW + v];
                for (int l = 0; l < 4; l++)
                    atomicAdd(&lh[__float_as_uint(sigmoidf_(s[l]) * cf[l]) >> 19], 1u);
            }
        }
    }
    __syncthreads();
    unsigned* gh = histF + b * NBIN1;
    for (int i = tid; i < NBIN1; i += 256) {
        unsigned v2 = lh[i];
        if (v2) atomicAdd(&gh[i], v2);
    }
}

// ---------------- fallback: find rank-400 bin (coarse) ---------------------
__global__ __launch_bounds__(256) void fb_cut(const unsigned* __restrict__ histF,
                                              unsigned* __restrict__ cutb,
                                              const unsigned* __restrict__ flags) {
    int b = blockIdx.x;
    if (flags[b]) return;
    __shared__ unsigned h[NBIN1];
    __shared__ unsigned resv[2];
    for (int i = threadIdx.x; i < NBIN1; i += 256) h[i] = histF[b * NBIN1 + i];
    __syncthreads();
    wave_select(h, NBIN1, KTOP, resv, threadIdx.x);
    __syncthreads();
    if (threadIdx.x == 0) cutb[b] = resv[0];
}

// ---------------- fallback: recompact with exact bin cut -------------------
__global__ __launch_bounds__(256) void fb_compact(
        const float* __restrict__ t0, const float* __restrict__ t1,
        const float* __restrict__ t2,
        const unsigned* __restrict__ cutb, unsigned* __restrict__ ccnt,
        unsigned* __restrict__ ckey, unsigned* __restrict__ cidx,
        const unsigned* __restrict__ flags)
{
    const int ba = blockIdx.z;
    const int b = ba / 3, a = ba - 3 * b;
    if (flags[b]) return;
    const int tid = threadIdx.x;
    const int c0 = blockIdx.y * 8;
    const int cx = blockIdx.x;
    unsigned cutkey = cutb[b] << 19;

    if (cx < 2) {
        const int hw = cx * 256 + tid;
        if (hw < 361) {
            const float* base = t0 + (size_t)(b * 255 + a * 85) * 361;
            float cf = sigmoidf_(base[4 * 361 + hw]);
            for (int u = 0; u < 8; u++) {
                float sc = sigmoidf_(base[(size_t)(5 + c0 + u) * 361 + hw]) * cf;
                unsigned key = __float_as_uint(sc);
                if (key >= cutkey) {
                    unsigned pos = atomicAdd(&ccnt[b], 1u);
                    if (pos < CAP) {
                        ckey[(size_t)b * CAP + pos] = key;
                        cidx[(size_t)b * CAP + pos] = (unsigned)((hw * NUMA + a) * NUMC + c0 + u);
                    }
                }
            }
        }
    } else {
        const float* tip; int vHW, v, candOff;
        if (cx < 4) { tip = t1; vHW = 361;  v = (cx - 2) * 256 + tid; candOff = 86640; }
        else        { tip = t2; vHW = 1444; v = (cx - 4) * 256 + tid; candOff = 433200; }
        if (v < vHW) {
            const f32x4* bp = (const f32x4*)(tip + (size_t)(b * 255 + a * 85) * (size_t)(vHW * 4));
            f32x4 cv = bp[(size_t)4 * vHW + v];
            float cf[4] = { sigmoidf_(cv[0]), sigmoidf_(cv[1]), sigmoidf_(cv[2]), sigmoidf_(cv[3]) };
            unsigned ib0 = (unsigned)(candOff + (v * 4 * NUMA + a) * NUMC + c0);
            for (int u = 0; u < 8; u++) {
                f32x4 s = bp[(size_t)(5 + c0 + u) * vHW + v];
                for (int l = 0; l < 4; l++) {
                    float sc = sigmoidf_(s[l]) * cf[l];
                    unsigned key = __float_as_uint(sc);
                    if (key >= cutkey) {
                        unsigned pos = atomicAdd(&ccnt[b], 1u);
                        if (pos < CAP) {
                            ckey[(size_t)b * CAP + pos] = key;
                            cidx[(size_t)b * CAP + pos] = ib0 + (unsigned)u + (unsigned)l * 240;
                        }
                    }
                }
            }
        }
    }
}

// ---------------- prefilter: keys >= cutfloor into small buffer ------------
__global__ __launch_bounds__(256) void prefilter(
        const unsigned* __restrict__ ckey, const unsigned* __restrict__ cidx,
        const unsigned* __restrict__ ccnt, const unsigned* __restrict__ cutfloor,
        unsigned* __restrict__ cnt2, unsigned* __restrict__ ckey2,
        unsigned* __restrict__ cidx2)
{
    __shared__ unsigned lk[LBUF], li[LBUF];
    __shared__ unsigned lcnt, lbase;
    const int tid = threadIdx.x;
    const int b = blockIdx.z;
    if (tid == 0) lcnt = 0;
    __syncthreads();
    const unsigned n = uminu(ccnt[b], (unsigned)CAP);
    const unsigned cutf = cutfloor[b];
    const unsigned* ck = ckey + (size_t)b * CAP;
    const unsigned* ci = cidx + (size_t)b * CAP;
    for (unsigned i = blockIdx.x * 256 + tid; i < n; i += 32 * 256) {
        unsigned k = ck[i];
        if (k >= cutf) {
            unsigned p = atomicAdd(&lcnt, 1u);
            if (p < LBUF) { lk[p] = k; li[p] = ci[i]; }
        }
    }
    __syncthreads();
    if (tid == 0) lbase = atomicAdd(&cnt2[b], uminu(lcnt, (unsigned)LBUF));
    __syncthreads();
    unsigned c = uminu(lcnt, (unsigned)LBUF);
    for (unsigned i = tid; i < c; i += 256) {
        unsigned p = lbase + i;
        if (p < CAP2) {
            ckey2[(size_t)b * CAP2 + p] = lk[i];
            cidx2[(size_t)b * CAP2 + p] = li[i];
        }
    }
}

// ---------------- topk: exact top-400 select + sort + box decode -----------
__global__ __launch_bounds__(512) void topk_kernel(
        const float* __restrict__ t0, const float* __restrict__ t1,
        const float* __restrict__ t2,
        const float* __restrict__ anc0, const float* __restrict__ anc1,
        const float* __restrict__ anc2,
        const unsigned* __restrict__ ckey, const unsigned* __restrict__ cidx,
        const unsigned* __restrict__ ccnt,
        const unsigned* __restrict__ ckey2, const unsigned* __restrict__ cidx2,
        const unsigned* __restrict__ cnt2,
        float* __restrict__ dX1, float* __restrict__ dY1,
        float* __restrict__ dX2, float* __restrict__ dY2,
        float* __restrict__ dSC, unsigned* __restrict__ dCID)
{
    const int b = blockIdx.x;
    const int tid = threadIdx.x;
    const int T = 512;

    __shared__ unsigned hist[4096];
    __shared__ unsigned resv[2];
    __shared__ unsigned selk[512], seli[512];
    __shared__ unsigned eqi[EQCAP];
    __shared__ unsigned cnts[2];

    unsigned n2 = cnt2[b];
    const unsigned* ck; const unsigned* ci; unsigned n;
    if (n2 <= (unsigned)CAP2) {
        ck = ckey2 + (size_t)b * CAP2; ci = cidx2 + (size_t)b * CAP2; n = n2;
    } else {
        ck = ckey + (size_t)b * CAP; ci = cidx + (size_t)b * CAP;
        n = uminu(ccnt[b], (unsigned)CAP);
    }

    // ---- Round 1: bits [30:19] ----
    for (int i = tid; i < NBIN1; i += T) hist[i] = 0;
    __syncthreads();
    for (unsigned i = tid; i < n; i += T) atomicAdd(&hist[ck[i] >> 19], 1u);
    __syncthreads();
    wave_select(hist, NBIN1, KTOP, resv, tid);
    __syncthreads();
    unsigned b1 = resv[0], r2 = resv[1];
    __syncthreads();

    // ---- Round 2: bits [18:7] ----
    for (int i = tid; i < 4096; i += T) hist[i] = 0;
    __syncthreads();
    for (unsigned i = tid; i < n; i += T) {
        unsigned k = ck[i];
        if ((k >> 19) == b1) atomicAdd(&hist[(k >> 7) & 0xFFFu], 1u);
    }
    __syncthreads();
    wave_select(hist, 4096, r2, resv, tid);
    __syncthreads();
    unsigned b2 = resv[0], r3 = resv[1];
    __syncthreads();

    // ---- Round 3: bits [6:0] ----
    for (int i = tid; i < 128; i += T) hist[i] = 0;
    __syncthreads();
    unsigned pref = (b1 << 12) | b2;
    for (unsigned i = tid; i < n; i += T) {
        unsigned k = ck[i];
        if ((k >> 7) == pref) atomicAdd(&hist[k & 127u], 1u);
    }
    __syncthreads();
    wave_select(hist, 128, r3, resv, tid);
    __syncthreads();
    unsigned b3 = resv[0], needEq = resv[1];
    unsigned K400 = (b1 << 19) | (b2 << 7) | b3;
    __syncthreads();

    // ---- compaction ----
    selk[tid] = 0u; seli[tid] = 0xFFFFFFFFu;
    for (int i = tid; i < EQCAP; i += T) eqi[i] = 0xFFFFFFFFu;
    if (tid == 0) { cnts[0] = 0; cnts[1] = 0; }
    __syncthreads();
    for (unsigned i = tid; i < n; i += T) {
        unsigned k = ck[i];
        if (k > K400) {
            unsigned p = atomicAdd(&cnts[0], 1u);
            if (p < KTOP) { selk[p] = k; seli[p] = ci[i]; }
        } else if (k == K400) {
            unsigned q = atomicAdd(&cnts[1], 1u);
            if (q < EQCAP) eqi[q] = ci[i];
        }
    }
    __syncthreads();
    unsigned selCnt = uminu(cnts[0], (unsigned)KTOP);
    unsigned eqN   = uminu(cnts[1], (unsigned)EQCAP);

    // ---- tie list: only sort if we must pick a strict subset ----
    if (eqN > needEq) {
        int P2 = 1; while ((unsigned)P2 < eqN) P2 <<= 1;
        for (int k2 = 2; k2 <= P2; k2 <<= 1) {
            for (int j = k2 >> 1; j > 0; j >>= 1) {
                __syncthreads();
                for (int i = tid; i < P2; i += T) {
                    int ixj = i ^ j;
                    if (ixj > i && ixj < P2) {
                        unsigned va = eqi[i], vb = eqi[ixj];
                        bool up = ((i & k2) == 0);
                        if (up ? (va > vb) : (va < vb)) { eqi[i] = vb; eqi[ixj] = va; }
                    }
                }
            }
        }
        __syncthreads();
    }
    for (unsigned t2v = tid; t2v < needEq; t2v += T) {
        unsigned p = selCnt + t2v;
        if (p < KTOP) { selk[p] = K400; seli[p] = eqi[t2v]; }
    }
    __syncthreads();

    // ---- bitonic sort 512 by (key desc, idx asc); j<64 passes in-wave ----
    for (int k2 = 2; k2 <= 512; k2 <<= 1) {
        int j = k2 >> 1;
        for (; j >= 64; j >>= 1) {
            __syncthreads();
            int i = tid, ixj = i ^ j;
            if (ixj > i) {
                unsigned ka = selk[i], kb = selk[ixj], ia = seli[i], ib = seli[ixj];
                bool before = (ka > kb) || (ka == kb && ia < ib);
                bool up = ((i & k2) == 0);
                if (up ? !before : before) {
                    selk[i] = kb; selk[ixj] = ka; seli[i] = ib; seli[ixj] = ia;
                }
            }
        }
        __syncthreads();
        for (; j > 0; j >>= 1) {
            int i = tid, ixj = i ^ j;
            if (ixj > i) {
                unsigned ka = selk[i], kb = selk[ixj], ia = seli[i], ib = seli[ixj];
                bool before = (ka > kb) || (ka == kb && ia < ib);
                bool up = ((i & k2) == 0);
                if (up ? !before : before) {
                    selk[i] = kb; selk[ixj] = ka; seli[i] = ib; seli[ixj] = ia;
                }
            }
        }
    }
    __syncthreads();

    // ---- gather + on-the-fly box decode; write det arrays (coalesced) ----
    if (tid < KTOP) {
        unsigned idx = seli[tid];
        const float* tip; const float* anc; int HW, W, candOff; float strideF;
        if (idx < 86640u)       { tip = t0; anc = anc0; HW = 361;  W = 19; strideF = 32.f; candOff = 0; }
        else if (idx < 433200u) { tip = t1; anc = anc1; HW = 1444; W = 38; strideF = 16.f; candOff = 86640; }
        else                    { tip = t2; anc = anc2; HW = 5776; W = 76; strideF = 8.f;  candOff = 433200; }
        unsigned local = idx - (unsigned)candOff;
        int cls = (int)(local % NUMC);
        int nn  = (int)(local / NUMC);
        int a = nn % NUMA, hwl = nn / NUMA;
        const float* base = tip + (size_t)(b * 255 + a * 85) * HW + hwl;
        float tx = base[0];
        float ty = base[(size_t)HW];
        float tw = base[(size_t)2 * HW];
        float th = base[(size_t)3 * HW];
        float fx = (float)(hwl % W), fy = (float)(hwl / W);
        float cx = (sigmoidf_(tx) + fx) * strideF;
        float cy = (sigmoidf_(ty) + fy) * strideF;
        float hw_ = expf(tw) * anc[2 * a]     * 0.5f;
        float hh_ = expf(th) * anc[2 * a + 1] * 0.5f;
        int o = b * KTOP + tid;
        dX1[o] = cx - hw_; dY1[o] = cy - hh_;
        dX2[o] = cx + hw_; dY2[o] = cy + hh_;
        dSC[o] = __uint_as_float(selk[tid]);
        dCID[o] = (unsigned)cls;
    }
}

// ---------------- mask: parallel suppression-bitmask build -----------------
// grid (11, 8): 2800 mask words per image over 11x256 threads.
__global__ __launch_bounds__(256) void mask_kernel(
        const float* __restrict__ dX1, const float* __restrict__ dY1,
        const float* __restrict__ dX2, const float* __restrict__ dY2,
        const unsigned* __restrict__ dCID, unsigned long long* __restrict__ maskG)
{
    __shared__ float lx1[KTOP], ly1[KTOP], lx2[KTOP], ly2[KTOP];
    __shared__ int lcid[KTOP];
    const int b = blockIdx.y;
    const int tid = threadIdx.x;
    for (int i = tid; i < KTOP; i += 256) {
        int o = b * KTOP + i;
        lx1[i] = dX1[o]; ly1[i] = dY1[o];
        lx2[i] = dX2[o]; ly2[i] = dY2[o];
        lcid[i] = (int)dCID[o];
    }
    __syncthreads();
    int p = blockIdx.x * 256 + tid;
    if (p < NMASK) {
        int i = p / 7, w = p - i * 7;
        float x1i = lx1[i], y1i = ly1[i], x2i = lx2[i], y2i = ly2[i];
        float ai = fmaxf(x2i - x1i, 0.f) * fmaxf(y2i - y1i, 0.f);
        int cidI = lcid[i];
        unsigned long long m = 0ull;
        int j0 = w * 64;
        int j1 = j0 + 64; if (j1 > KTOP) j1 = KTOP;
        int js = j0 > i + 1 ? j0 : i + 1;
        for (int j = js; j < j1; j++) {
            if (lcid[j] != cidI) continue;
            float iw = fminf(x2i, lx2[j]) - fmaxf(x1i, lx1[j]);
            float ih = fminf(y2i, ly2[j]) - fmaxf(y1i, ly1[j]);
            iw = fmaxf(iw, 0.f); ih = fmaxf(ih, 0.f);
            float inter = iw * ih;
            float aj = fmaxf(lx2[j] - lx1[j], 0.f) * fmaxf(ly2[j] - ly1[j], 0.f);
            float iou = inter / (ai + aj - inter + 1e-12f);
            if (iou > 0.45f) m |= (1ull << (j - j0));
        }
        maskG[(size_t)b * NMASK + p] = m;
    }
}

// ---------------- greedy + output: 8-deep prefetch ring --------------------
__global__ __launch_bounds__(512) void greedy_kernel(
        const float* __restrict__ dX1, const float* __restrict__ dY1,
        const float* __restrict__ dX2, const float* __restrict__ dY2,
        const float* __restrict__ dSC, const unsigned* __restrict__ dCID,
        const unsigned long long* __restrict__ maskG, float* __restrict__ out)
{
    __shared__ unsigned long long maskL[NMASK];
    __shared__ unsigned long long vkeep[7];
    __shared__ float oid[POST], osc[POST], obb[POST * 4];
    const int b = blockIdx.x;
    const int tid = threadIdx.x;

    for (int i = tid; i < NMASK; i += 512) maskL[i] = maskG[(size_t)b * NMASK + i];
    if (tid < POST) { oid[tid] = -1.f; osc[tid] = -1.f; }
    if (tid < POST * 4) obb[tid] = -1.f;
    __syncthreads();

    if (tid < 64) {
        const int lane = tid;
        unsigned long long keep = 0ull;
        if (lane < 7) keep = (lane == 6) ? 0xFFFFull : ~0ull;
        unsigned long long mb[8];
        #pragma unroll
        for (int k = 0; k < 8; k++)
            mb[k] = (lane < 7) ? maskL[k * 7 + lane] : 0ull;
        for (int ib = 0; ib < KTOP; ib += 8) {
            #pragma unroll
            for (int k = 0; k < 8; k++) {
                int i = ib + k;
                unsigned long long m = mb[k];
                int nf = ib + 8 + k;
                mb[k] = (lane < 7 && nf < KTOP) ? maskL[nf * 7 + lane] : 0ull;
                int w = i >> 6;  // wave-uniform
                unsigned klo = (unsigned)__builtin_amdgcn_readlane((int)(unsigned)(keep & 0xFFFFFFFFull), w);
                unsigned khi = (unsigned)__builtin_amdgcn_readlane((int)(unsigned)(keep >> 32), w);
                unsigned long long kw = ((unsigned long long)khi << 32) | klo;
                if ((kw >> (i & 63)) & 1ull) keep &= ~m;
            }
        }
        if (lane < 7) vkeep[lane] = keep;
    }
    __syncthreads();

    if (tid < KTOP) {
        int w = tid >> 6, bp = tid & 63;
        unsigned long long kw = vkeep[w];
        if ((kw >> bp) & 1ull) {
            int r = 0;
            for (int q = 0; q < w; q++) r += __popcll(vkeep[q]);
            r += __popcll(kw & ((1ull << bp) - 1ull));
            if (r < POST) {
                int o = b * KTOP + tid;
                oid[r] = (float)(int)dCID[o];
                osc[r] = dSC[o];
                obb[r * 4 + 0] = dX1[o];
                obb[r * 4 + 1] = dY1[o];
                obb[r * 4 + 2] = dX2[o];
                obb[r * 4 + 3] = dY2[o];
            }
        }
    }
    __syncthreads();
    if (tid < POST) {
        out[b * POST + tid]       = oid[tid];
        out[800 + b * POST + tid] = osc[tid];
    }
    if (tid < POST * 4) out[1600 + b * POST * 4 + tid] = obb[tid];
}

// ---------------------------------------------------------------------------
extern "C" void kernel_launch(void* const* d_in, const int* in_sizes, int n_in,
                              void* d_out, int out_size, void* d_ws, size_t ws_size,
                              hipStream_t stream)
{
    const float* tip0 = (const float*)d_in[0];
    const float* tip1 = (const float*)d_in[1];
    const float* tip2 = (const float*)d_in[2];
    const float* anc0 = (const float*)d_in[3];
    const float* anc1 = (const float*)d_in[4];
    const float* anc2 = (const float*)d_in[5];
    float* out = (float*)d_out;

    // ws layout (u32 unless noted): histN(16K) | histF(16K) | cutb(8) |
    // cutfloor(8) | ccnt(8) | cnt2(8) | flags(8) | ckey(8*CAP) | cidx(8*CAP) |
    // ckey2(8*CAP2) | cidx2(8*CAP2) | det 6x3200 f32 | maskG 8*2800 u64
    unsigned* histN    = (unsigned*)d_ws;
    unsigned* histF    = histN + 8 * NBIN1;
    unsigned* cutb     = histF + 8 * NBIN1;
    unsigned* cutfloor = cutb + 8;
    unsigned* ccnt     = cutfloor + 8;
    unsigned* cnt2     = ccnt + 8;
    unsigned* flags    = cnt2 + 8;
    unsigned* ckey     = flags + 8;
    unsigned* cidx     = ckey + (size_t)8 * CAP;
    unsigned* ckey2    = cidx + (size_t)8 * CAP;
    unsigned* cidx2    = ckey2 + (size_t)8 * CAP2;
    float*    dX1      = (float*)(cidx2 + (size_t)8 * CAP2);
    float*    dY1      = dX1 + 8 * KTOP;
    float*    dX2      = dY1 + 8 * KTOP;
    float*    dY2      = dX2 + 8 * KTOP;
    float*    dSC      = dY2 + 8 * KTOP;
    unsigned* dCID     = (unsigned*)(dSC + 8 * KTOP);
    unsigned long long* maskG = (unsigned long long*)(dCID + 8 * KTOP);

    init_kernel<<<(NBIN1 * 16 + 40 + 255) / 256, 256, 0, stream>>>(histN);

    dim3 g(10, 10, 24);
    score_main<<<g, 256, 0, stream>>>(tip0, tip1, tip2, ccnt, ckey, cidx, histN);
    findcut_v<<<8, 256, 0, stream>>>(histN, cutfloor, ccnt, flags);
    fb_hist<<<g, 256, 0, stream>>>(tip0, tip1, tip2, histF, flags);
    fb_cut<<<8, 256, 0, stream>>>(histF, cutb, flags);
    fb_compact<<<g, 256, 0, stream>>>(tip0, tip1, tip2, cutb, ccnt, ckey, cidx, flags);
    prefilter<<<dim3(32, 1, 8), 256, 0, stream>>>(ckey, cidx, ccnt, cutfloor,
                                                  cnt2, ckey2, cidx2);
    topk_kernel<<<8, 512, 0, stream>>>(tip0, tip1, tip2, anc0, anc1, anc2,
                                       ckey, cidx, ccnt, ckey2, cidx2, cnt2,
                                       dX1, dY1, dX2, dY2, dSC, dCID);
    mask_kernel<<<dim3((NMASK + 255) / 256, 8), 256, 0, stream>>>(
        dX1, dY1, dX2, dY2, dCID, maskG);
    greedy_kernel<<<8, 512, 0, stream>>>(dX1, dY1, dX2, dY2, dSC, dCID, maskG, out);
}